// Round 3
// baseline (2824.789 us; speedup 1.0000x reference)
//
#include <hip/hip_runtime.h>
#include <stdint.h>

// Problem constants (B=4, L=2048, D=2048)
#define B_DIM 4
#define L_DIM 2048
#define D_DIM 2048
#define M_DIM 8192              // B*L token rows
#define K_DIM 2048
#define N_DIM 2048
#define WELEM (D_DIM * D_DIM)   // 4194304 elements per weight
#define CHUNK 32
#define NCH (L_DIM / CHUNK)     // 64 chunks per sequence

typedef int v4i  __attribute__((ext_vector_type(4)));
typedef int v16i __attribute__((ext_vector_type(16)));
typedef unsigned short bfraw;   // bf16 bit pattern

#define AS1 __attribute__((address_space(1)))
#define AS3 __attribute__((address_space(3)))

__device__ __forceinline__ void gl_lds16(const void* g, void* l) {
    // async global->LDS, 16B per lane; LDS dst = wave-uniform base + lane*16
    __builtin_amdgcn_global_load_lds((AS1 void*)g, (AS3 void*)l, 16, 0, 0);
}

// raw workgroup barrier WITHOUT implicit vmcnt(0) drain (unlike __syncthreads)
__device__ __forceinline__ void wg_barrier() {
    asm volatile("" ::: "memory");
    __builtin_amdgcn_s_barrier();
    asm volatile("" ::: "memory");
}

__device__ __forceinline__ float sigmoidf_(float x) { return 1.0f / (1.0f + expf(-x)); }

__device__ __forceinline__ float bf2f(bfraw u) {
    union { unsigned int i; float f; } c; c.i = ((unsigned int)u) << 16; return c.f;
}
__device__ __forceinline__ bfraw f2bf(float f) {
    union { float f; unsigned int i; } c; c.f = f;
    unsigned int lsb = (c.i >> 16) & 1;
    c.i += 0x7fffu + lsb;                   // round-to-nearest-even
    return (bfraw)(c.i >> 16);
}

__device__ __forceinline__ void store_out(float* p, float v) { *p = v; }
__device__ __forceinline__ void store_out(bfraw* p, float v) { *p = f2bf(v); }

// ---------------- block reductions (256 threads = 4 waves) ----------------
__device__ __forceinline__ float block_sum256(float v) {
#pragma unroll
    for (int off = 32; off > 0; off >>= 1) v += __shfl_down(v, off);
    __shared__ float sb[4];
    int lane = threadIdx.x & 63, wv = threadIdx.x >> 6;
    __syncthreads();
    if (lane == 0) sb[wv] = v;
    __syncthreads();
    return sb[0] + sb[1] + sb[2] + sb[3];
}

__device__ __forceinline__ void block_sum_max256(float& s, float& m) {
#pragma unroll
    for (int off = 32; off > 0; off >>= 1) {
        s += __shfl_down(s, off);
        m = fmaxf(m, __shfl_down(m, off));
    }
    __shared__ float sb2[8];
    int lane = threadIdx.x & 63, wv = threadIdx.x >> 6;
    __syncthreads();
    if (lane == 0) { sb2[wv] = s; sb2[4 + wv] = m; }
    __syncthreads();
    s = sb2[0] + sb2[1] + sb2[2] + sb2[3];
    m = fmaxf(fmaxf(sb2[4], sb2[5]), fmaxf(sb2[6], sb2[7]));
}

// ---------------- weight stats: mean|W| per weight ----------------
__global__ void wstats1(const float* __restrict__ w0, const float* __restrict__ w1,
                        const float* __restrict__ w2, const float* __restrict__ w3,
                        float* __restrict__ wpart) {
    int w = blockIdx.x >> 7;
    int slice = blockIdx.x & 127;
    const float* W = (w == 0) ? w0 : ((w == 1) ? w1 : ((w == 2) ? w2 : w3));
    const float4* p = (const float4*)(W + (size_t)slice * (WELEM / 128));
    float s = 0.f;
    for (int i = threadIdx.x; i < (WELEM / 128 / 4); i += 256) {
        float4 v = p[i];
        s += fabsf(v.x) + fabsf(v.y) + fabsf(v.z) + fabsf(v.w);
    }
    s = block_sum256(s);
    if (threadIdx.x == 0) wpart[blockIdx.x] = s;
}

__global__ void wstats2(const float* __restrict__ wpart, float* __restrict__ wdeq) {
    int w = threadIdx.x >> 6;
    int lane = threadIdx.x & 63;
    float s = wpart[w * 128 + lane] + wpart[w * 128 + 64 + lane];
#pragma unroll
    for (int off = 32; off > 0; off >>= 1) s += __shfl_down(s, off);
    if (lane == 0) wdeq[w] = fmaxf(s * (1.0f / (float)WELEM), 1e-5f);
}

// ---------------- merged: weight ternary quant (blocks 0..16383) + act quant ------
__global__ void quant_all(const float* __restrict__ w0, const float* __restrict__ w1,
                          const float* __restrict__ w2, const float* __restrict__ w3,
                          const float* __restrict__ wdeq, int8_t* __restrict__ wq,
                          const float* __restrict__ x, int8_t* __restrict__ xq,
                          float* __restrict__ adeq) {
    if (blockIdx.x < 16384) {
        // ----- weight ternary quantization: one float4 group per thread -----
        size_t idx = (size_t)blockIdx.x * 256 + threadIdx.x;
        int w = (int)(idx >> 20);                               // WELEM/4 = 2^20 groups/weight
        size_t g = idx & ((1u << 20) - 1);
        const float* W = (w == 0) ? w0 : ((w == 1) ? w1 : ((w == 2) ? w2 : w3));
        float inv = 1.0f / wdeq[w];                             // = ws
        float4 v = ((const float4*)W)[g];
        int q0 = (int)rintf(v.x * inv); q0 = q0 < -1 ? -1 : (q0 > 1 ? 1 : q0);
        int q1 = (int)rintf(v.y * inv); q1 = q1 < -1 ? -1 : (q1 > 1 ? 1 : q1);
        int q2 = (int)rintf(v.z * inv); q2 = q2 < -1 ? -1 : (q2 > 1 ? 1 : q2);
        int q3 = (int)rintf(v.w * inv); q3 = q3 < -1 ? -1 : (q3 > 1 ? 1 : q3);
        uint32_t p = (uint32_t)(q0 & 0xff) | ((uint32_t)(q1 & 0xff) << 8) |
                     ((uint32_t)(q2 & 0xff) << 16) | ((uint32_t)(q3 & 0xff) << 24);
        ((uint32_t*)(wq + (size_t)w * WELEM))[g] = p;
        return;
    }
    // ----- activation rmsnorm + int8 quant (one row per block) -----
    int row = blockIdx.x - 16384, tid = threadIdx.x;
    const float4* xr = (const float4*)(x + (size_t)row * D_DIM);
    float4 a = xr[2 * tid], b = xr[2 * tid + 1];
    float v[8] = {a.x, a.y, a.z, a.w, b.x, b.y, b.z, b.w};
    float ss = 0.f, mx = 0.f;
#pragma unroll
    for (int j = 0; j < 8; j++) { ss += v[j] * v[j]; mx = fmaxf(mx, fabsf(v[j])); }
    block_sum_max256(ss, mx);
    float inv = rsqrtf(ss * (1.0f / (float)D_DIM) + 1e-5f);
    float anc = fmaxf(mx * inv, 1e-5f);      // max|xn| clipped
    float s = 127.0f / anc;
    if (tid == 0) adeq[row] = anc * (1.0f / 127.0f);
    float sc = inv * s;
    int q[8];
#pragma unroll
    for (int j = 0; j < 8; j++) {
        int t = (int)rintf(v[j] * sc);
        q[j] = t < -128 ? -128 : (t > 127 ? 127 : t);
    }
    uint32_t lo = (uint32_t)(q[0] & 0xff) | ((uint32_t)(q[1] & 0xff) << 8) |
                  ((uint32_t)(q[2] & 0xff) << 16) | ((uint32_t)(q[3] & 0xff) << 24);
    uint32_t hi = (uint32_t)(q[4] & 0xff) | ((uint32_t)(q[5] & 0xff) << 8) |
                  ((uint32_t)(q[6] & 0xff) << 16) | ((uint32_t)(q[7] & 0xff) << 24);
    ((uint2*)(xq + (size_t)row * D_DIM))[tid] = make_uint2(lo, hi);
}

// ---------------- int8 x ternary GEMM core: 128x256 tile, BK=64B, 4 waves ---------
// Wave wv: wm=(wv&1)*64 (2 m-groups of 32), wn=(wv>>1)*128 (4 n-groups of 32).
// mfma_i32_32x32x32_i8: per K-iter, 2 k-steps x (2 m x 4 n) = 16 MFMA/wave.
//
// r3 restructure (occupancy + LDS-pipe relief):
//  - A operand loads DIRECTLY global->VGPR (4 dwordx4/wave/iter, per-lane
//    fragment addresses row=l&31, kchunk=l>>5 -- same permutation as before).
//    Wave pairs read identical A lines -> L1 dedups.  Removes A from LDS.
//  - B stays in LDS via global_load_lds, fragment-order, double-buffered:
//    LDS/block = 2 x 16 KB = 32 KB  ->  up to 5 blocks/CU (was 48 KB @ 2).
//  - counted vmcnt(8) = 4 B-stages + 4 A-loads of the NEXT tile in flight;
//    never drains to 0 in the main loop.  2 raw barriers/iter.
#define BM 128
#define BN 256
#define BKB 64

#define MFMA32(a, b, c) __builtin_amdgcn_mfma_i32_32x32x32_i8((a), (b), (c), 0, 0, 0)

template <typename OutT>
__device__ __forceinline__ void gemm_core(
    const int8_t* __restrict__ A, const int8_t* __restrict__ Bw,
    const float* __restrict__ adeq, float wsc,
    int m0, int n0, OutT* __restrict__ Cout) {
    __shared__ __align__(16) int8_t sB[2][BN * BKB];   // 2 x 16 KB, 8 groups of 2KB
    int lane = threadIdx.x & 63;
    int wv = threadIdx.x >> 6;
    int wm = (wv & 1) * 64;          // wave's 2 A m-groups
    int wn = (wv >> 1) * 128;        // wave's 4 B n-groups
    int r32 = lane & 31;             // row within a 32-row group
    int h32 = lane >> 5;             // 16B k-chunk half selector

    const v16i vzero = {0, 0, 0, 0, 0, 0, 0, 0, 0, 0, 0, 0, 0, 0, 0, 0};
    v16i acc[2][4];
#pragma unroll
    for (int m = 0; m < 2; m++)
#pragma unroll
        for (int j = 0; j < 4; j++) acc[m][j] = vzero;

    // per-lane fragment base addresses (row = r32, k-chunk = h32)
    const int8_t* Adir = A + (size_t)(m0 + wm + r32) * K_DIM + h32 * 16;
    const int8_t* Bsrc = Bw + (size_t)(n0 + r32) * K_DIM + h32 * 16;
    const int bg = (wv >> 1) * 4;    // this wave's first B group

    // wave wv stages B groups 2wv, 2wv+1 (4 gl_lds = 4 KB)
#define STAGE_B(c, kt) do {                                                                      \
    gl_lds16(Bsrc + (size_t)((2 * wv) * 32) * K_DIM + (kt),          &sB[c][(2 * wv) * 2048]);          \
    gl_lds16(Bsrc + (size_t)((2 * wv) * 32) * K_DIM + (kt) + 32,     &sB[c][(2 * wv) * 2048 + 1024]);   \
    gl_lds16(Bsrc + (size_t)((2 * wv + 1) * 32) * K_DIM + (kt),      &sB[c][(2 * wv + 1) * 2048]);      \
    gl_lds16(Bsrc + (size_t)((2 * wv + 1) * 32) * K_DIM + (kt) + 32, &sB[c][(2 * wv + 1) * 2048 + 1024]); \
  } while (0)

    // A fragments for tile kt -> register set AC (4 x dwordx4)
#define LOAD_A(AC, kt) do {                                                       \
    _Pragma("unroll") for (int m_ = 0; m_ < 2; m_++)                              \
    _Pragma("unroll") for (int k_ = 0; k_ < 2; k_++)                              \
        AC[m_][k_] = *(const v4i*)(Adir + (size_t)(m_ * 32) * K_DIM + (kt) + k_ * 32); \
  } while (0)

    // one K-iter: consume buf c + regs AC for tile kt; prefetch tile kt+2*BKB
#define GBODY(c, AC, kt) do {                                                     \
    v4i bf[4][2];                                                                 \
    _Pragma("unroll") for (int j_ = 0; j_ < 4; j_++)                              \
    _Pragma("unroll") for (int k_ = 0; k_ < 2; k_++)                              \
        bf[j_][k_] = *(const v4i*)(&sB[c][(bg + j_) * 2048 + k_ * 1024 + lane * 16]); \
    __builtin_amdgcn_s_setprio(1);                                                \
    _Pragma("unroll") for (int j_ = 0; j_ < 4; j_++) {                            \
        acc[0][j_] = MFMA32(AC[0][0], bf[j_][0], acc[0][j_]);                     \
        acc[1][j_] = MFMA32(AC[1][0], bf[j_][0], acc[1][j_]);                     \
        acc[0][j_] = MFMA32(AC[0][1], bf[j_][1], acc[0][j_]);                     \
        acc[1][j_] = MFMA32(AC[1][1], bf[j_][1], acc[1][j_]);                     \
    }                                                                             \
    __builtin_amdgcn_s_setprio(0);                                                \
    wg_barrier();                 /* all waves done reading sB[c] */              \
    if ((kt) + 2 * BKB < K_DIM) { STAGE_B(c, (kt) + 2 * BKB); LOAD_A(AC, (kt) + 2 * BKB); } \
    if ((kt) + BKB < K_DIM) {                                                     \
        if ((kt) + 2 * BKB < K_DIM)                                               \
            asm volatile("s_waitcnt vmcnt(8)" ::: "memory");  /* tile kt+1 landed */ \
        else                                                                      \
            asm volatile("s_waitcnt vmcnt(0)" ::: "memory");                      \
        wg_barrier();                                                             \
    }                                                                             \
  } while (0)

    v4i a0[2][2], a1[2][2];
    STAGE_B(0, 0);      LOAD_A(a0, 0);        // tile 0
    STAGE_B(1, BKB);    LOAD_A(a1, BKB);      // tile 1
    asm volatile("s_waitcnt vmcnt(8)" ::: "memory");   // tile 0 landed, tile 1 in flight
    wg_barrier();

    for (int kt = 0; kt < K_DIM; kt += 2 * BKB) {
        GBODY(0, a0, kt);
        GBODY(1, a1, kt + BKB);
    }
#undef GBODY
#undef LOAD_A
#undef STAGE_B

    // C/D 32x32 layout: col = lane&31 (N/W side), row = (r&3)+8*(r>>2)+4*(lane>>5)
#pragma unroll
    for (int m = 0; m < 2; m++) {
#pragma unroll
        for (int r = 0; r < 16; r++) {
            int rr = (r & 3) + 8 * (r >> 2) + 4 * h32;
            int row = m0 + wm + m * 32 + rr;
            float rs = adeq[row] * wsc;
            OutT* crow = Cout + (size_t)row * N_DIM + n0 + wn + r32;
#pragma unroll
            for (int j = 0; j < 4; j++) store_out(crow + j * 32, (float)acc[m][j][r] * rs);
        }
    }
}

// merged i/f/g GEMM: grid.x = 24 (8 N-tiles x 3 weights), grid.y = 64 M-tiles
__global__ __launch_bounds__(256, 4) void gemm_ifg(
    const int8_t* __restrict__ xq, const int8_t* __restrict__ wq,
    const float* __restrict__ adeq, const float* __restrict__ wdeq,
    bfraw* __restrict__ bufI, bfraw* __restrict__ bufF, bfraw* __restrict__ bufG) {
    int widx = blockIdx.x >> 3;
    int n0 = (blockIdx.x & 7) * BN;
    int m0 = blockIdx.y * BM;
    bfraw* outp = (widx == 0) ? bufI : ((widx == 1) ? bufF : bufG);
    gemm_core<bfraw>(xq, wq + (size_t)widx * WELEM, adeq, wdeq[widx], m0, n0, outp);
}

// final o GEMM: fp32 out. grid.x = 8, grid.y = 64
__global__ __launch_bounds__(256, 4) void gemm_o(
    const int8_t* __restrict__ oq, const int8_t* __restrict__ wq,
    const float* __restrict__ odeq, const float* __restrict__ wdeq,
    float* __restrict__ out) {
    gemm_core<float>(oq, wq + 3 * (size_t)WELEM, odeq, wdeq[3], blockIdx.y * BM,
                     blockIdx.x * BN, out);
}

// ---------------- chunked scan with fused activations ----------------
// f_t = sigmoid(fL_t); i_t = silu(iL_t)*(1-f_t); h_t = f_t*h_{t-1} + i_t
__global__ void scan1(const bfraw* __restrict__ iL, const bfraw* __restrict__ fL,
                      float* __restrict__ Fc, float* __restrict__ Ic) {
    int idx = blockIdx.x * 256 + threadIdx.x;   // 4*64*2048
    int d = idx & (D_DIM - 1);
    int c = (idx >> 11) & (NCH - 1);
    int b = idx >> 17;
    size_t base = ((size_t)(b * L_DIM + c * CHUNK)) * D_DIM + d;
    float F = 1.f, h = 0.f;
#pragma unroll 4
    for (int t = 0; t < CHUNK; t++) {
        float fr = bf2f(fL[base + (size_t)t * D_DIM]);
        float ir = bf2f(iL[base + (size_t)t * D_DIM]);
        float fv = sigmoidf_(fr);
        float iv = ir * sigmoidf_(ir) * (1.0f - fv);
        h = fv * h + iv;
        F *= fv;
    }
    size_t ci = ((size_t)b * NCH + c) * D_DIM + d;
    Fc[ci] = F;
    Ic[ci] = h;
}

__global__ void scan2(const float* __restrict__ Fc, const float* __restrict__ Ic,
                      float* __restrict__ Hc) {
    int idx = blockIdx.x * 256 + threadIdx.x;   // 8192
    int d = idx & (D_DIM - 1);
    int b = idx >> 11;
    float h = 0.f;
    for (int c0 = 0; c0 < NCH; c0 += 8) {
        float F[8], I[8];
#pragma unroll
        for (int j = 0; j < 8; j++) {
            size_t ci = ((size_t)b * NCH + c0 + j) * D_DIM + d;
            F[j] = Fc[ci];
            I[j] = Ic[ci];
        }
#pragma unroll
        for (int j = 0; j < 8; j++) {
            size_t ci = ((size_t)b * NCH + c0 + j) * D_DIM + d;
            Hc[ci] = h;
            h = F[j] * h + I[j];
        }
    }
}

__global__ void scan3(const bfraw* __restrict__ iL, const bfraw* __restrict__ fL,
                      const float* __restrict__ Hc, bfraw* __restrict__ hout) {
    int idx = blockIdx.x * 256 + threadIdx.x;
    int d = idx & (D_DIM - 1);
    int c = (idx >> 11) & (NCH - 1);
    int b = idx >> 17;
    size_t base = ((size_t)(b * L_DIM + c * CHUNK)) * D_DIM + d;
    float h = Hc[((size_t)b * NCH + c) * D_DIM + d];
#pragma unroll 4
    for (int t = 0; t < CHUNK; t++) {
        size_t a = base + (size_t)t * D_DIM;
        float fr = bf2f(fL[a]);
        float ir = bf2f(iL[a]);
        float fv = sigmoidf_(fr);
        float iv = ir * sigmoidf_(ir) * (1.0f - fv);
        h = fv * h + iv;
        hout[a] = f2bf(h);
    }
}

// ---------------- g-path: o = rmsnorm(g)*gw * h*sigmoid(h); rmsnorm+quant o ---------
union BF8 { uint4 u; bfraw s[8]; };

__global__ void gout_quant(const bfraw* __restrict__ gL, const bfraw* __restrict__ h,
                           const float* __restrict__ gw, int8_t* __restrict__ oq,
                           float* __restrict__ odeq) {
    int row = blockIdx.x, tid = threadIdx.x;
    BF8 g8, h8;
    g8.u = ((const uint4*)(gL + (size_t)row * D_DIM))[tid];
    float gv[8];
    float ss = 0.f;
#pragma unroll
    for (int j = 0; j < 8; j++) { gv[j] = bf2f(g8.s[j]); ss += gv[j] * gv[j]; }
    float ssg = block_sum256(ss);
    float invg = rsqrtf(ssg * (1.0f / (float)D_DIM) + 1e-5f);

    h8.u = ((const uint4*)(h + (size_t)row * D_DIM))[tid];
    const float4* wr = (const float4*)gw;
    float4 w0 = wr[2 * tid], w1 = wr[2 * tid + 1];
    float wv[8] = {w0.x, w0.y, w0.z, w0.w, w1.x, w1.y, w1.z, w1.w};
    float o[8];
    float sso = 0.f, amax = 0.f;
#pragma unroll
    for (int j = 0; j < 8; j++) {
        float hv = bf2f(h8.s[j]);
        o[j] = gv[j] * invg * wv[j] * hv * sigmoidf_(hv);
        sso += o[j] * o[j];
        amax = fmaxf(amax, fabsf(o[j]));
    }
    block_sum_max256(sso, amax);
    float invo = rsqrtf(sso * (1.0f / (float)D_DIM) + 1e-5f);
    float anc = fmaxf(amax * invo, 1e-5f);
    float s = 127.0f / anc;
    if (tid == 0) odeq[row] = anc * (1.0f / 127.0f);
    float sc = invo * s;
    int q[8];
#pragma unroll
    for (int j = 0; j < 8; j++) {
        int t = (int)rintf(o[j] * sc);
        q[j] = t < -128 ? -128 : (t > 127 ? 127 : t);
    }
    uint32_t lo = (uint32_t)(q[0] & 0xff) | ((uint32_t)(q[1] & 0xff) << 8) |
                  ((uint32_t)(q[2] & 0xff) << 16) | ((uint32_t)(q[3] & 0xff) << 24);
    uint32_t hi = (uint32_t)(q[4] & 0xff) | ((uint32_t)(q[5] & 0xff) << 8) |
                  ((uint32_t)(q[6] & 0xff) << 16) | ((uint32_t)(q[7] & 0xff) << 24);
    ((uint2*)(oq + (size_t)row * D_DIM))[tid] = make_uint2(lo, hi);
}

// ---------------- driver ----------------
extern "C" void kernel_launch(void* const* d_in, const int* in_sizes, int n_in,
                              void* d_out, int out_size, void* d_ws, size_t ws_size,
                              hipStream_t stream) {
    const float* x  = (const float*)d_in[0];
    const float* Wi = (const float*)d_in[1];
    const float* Wf = (const float*)d_in[2];
    const float* Wg = (const float*)d_in[3];
    const float* Wo = (const float*)d_in[4];
    const float* gw = (const float*)d_in[5];
    float* out = (float*)d_out;

    char* ws = (char*)d_ws;
    float*  wdeq  = (float*)(ws + 0);                 // 4 floats
    float*  wpart = (float*)(ws + 256);               // 512 partials
    float*  adeq  = (float*)(ws + 0x10000);           // 8192 per-row act dequant
    float*  odeq  = (float*)(ws + 0x20000);           // 8192 per-row o dequant
    int8_t* xq    = (int8_t*)(ws + 0x100000);         // 16MB int8 x; reused as oq
    int8_t* wq    = (int8_t*)(ws + 0x1100000);        // 4 x 4MB ternary weights
    float*  Fc    = (float*)(ws + 0x2100000);         // 2MB chunk f-products
    float*  Ic    = (float*)(ws + 0x2300000);         // 2MB chunk partial h
    float*  Hc    = (float*)(ws + 0x2500000);         // 2MB chunk carries
    bfraw*  bufI  = (bfraw*)(ws + 0x4000000);         // 32MB bf16: i_lin
    bfraw*  bufF  = (bfraw*)(ws + 0x6000000);         // 32MB bf16: f_lin
    bfraw*  bufG  = (bfraw*)(ws + 0x8000000);         // 32MB bf16: g_lin
    bfraw*  hbuf  = (bfraw*)(ws + 0xA000000);         // 32MB bf16: h

    wstats1<<<512, 256, 0, stream>>>(Wi, Wf, Wg, Wo, wpart);
    wstats2<<<1, 256, 0, stream>>>(wpart, wdeq);
    quant_all<<<16384 + 8192, 256, 0, stream>>>(Wi, Wf, Wg, Wo, wdeq, wq, x, xq, adeq);

    gemm_ifg<<<dim3(24, M_DIM / BM), 256, 0, stream>>>(xq, wq, adeq, wdeq, bufI, bufF, bufG);

    scan1<<<2048, 256, 0, stream>>>(bufI, bufF, Fc, Ic);
    scan2<<<32, 256, 0, stream>>>(Fc, Ic, Hc);
    scan3<<<2048, 256, 0, stream>>>(bufI, bufF, Hc, hbuf);

    gout_quant<<<M_DIM, 256, 0, stream>>>(bufG, hbuf, gw, xq /*as oq*/, odeq);
    gemm_o<<<dim3(N_DIM / BN, M_DIM / BM), 256, 0, stream>>>(xq /*oq*/, wq, odeq, wdeq, out);

    (void)in_sizes; (void)n_in; (void)out_size; (void)ws_size;
}

// Round 4
// 536.459 us; speedup vs baseline: 5.2656x; 5.2656x over previous
//
#include <hip/hip_runtime.h>
#include <stdint.h>

// Problem constants (B=4, L=2048, D=2048)
#define B_DIM 4
#define L_DIM 2048
#define D_DIM 2048
#define M_DIM 8192              // B*L token rows
#define K_DIM 2048
#define N_DIM 2048
#define WELEM (D_DIM * D_DIM)   // 4194304 elements per weight
#define CHUNK 32
#define NCH (L_DIM / CHUNK)     // 64 chunks per sequence

typedef int v4i  __attribute__((ext_vector_type(4)));
typedef int v16i __attribute__((ext_vector_type(16)));
typedef unsigned short bfraw;   // bf16 bit pattern

#define AS1 __attribute__((address_space(1)))
#define AS3 __attribute__((address_space(3)))

__device__ __forceinline__ void gl_lds16(const void* g, void* l) {
    // async global->LDS, 16B per lane; LDS dst = wave-uniform base + lane*16
    __builtin_amdgcn_global_load_lds((AS1 void*)g, (AS3 void*)l, 16, 0, 0);
}

// raw workgroup barrier WITHOUT implicit vmcnt(0) drain (unlike __syncthreads)
__device__ __forceinline__ void wg_barrier() {
    asm volatile("" ::: "memory");
    __builtin_amdgcn_s_barrier();
    asm volatile("" ::: "memory");
}

__device__ __forceinline__ float sigmoidf_(float x) { return 1.0f / (1.0f + expf(-x)); }

__device__ __forceinline__ float bf2f(bfraw u) {
    union { unsigned int i; float f; } c; c.i = ((unsigned int)u) << 16; return c.f;
}
__device__ __forceinline__ bfraw f2bf(float f) {
    union { float f; unsigned int i; } c; c.f = f;
    unsigned int lsb = (c.i >> 16) & 1;
    c.i += 0x7fffu + lsb;                   // round-to-nearest-even
    return (bfraw)(c.i >> 16);
}

__device__ __forceinline__ void store_out(float* p, float v) { *p = v; }
__device__ __forceinline__ void store_out(bfraw* p, float v) { *p = f2bf(v); }

// ---------------- block reductions (256 threads = 4 waves) ----------------
__device__ __forceinline__ float block_sum256(float v) {
#pragma unroll
    for (int off = 32; off > 0; off >>= 1) v += __shfl_down(v, off);
    __shared__ float sb[4];
    int lane = threadIdx.x & 63, wv = threadIdx.x >> 6;
    __syncthreads();
    if (lane == 0) sb[wv] = v;
    __syncthreads();
    return sb[0] + sb[1] + sb[2] + sb[3];
}

__device__ __forceinline__ void block_sum_max256(float& s, float& m) {
#pragma unroll
    for (int off = 32; off > 0; off >>= 1) {
        s += __shfl_down(s, off);
        m = fmaxf(m, __shfl_down(m, off));
    }
    __shared__ float sb2[8];
    int lane = threadIdx.x & 63, wv = threadIdx.x >> 6;
    __syncthreads();
    if (lane == 0) { sb2[wv] = s; sb2[4 + wv] = m; }
    __syncthreads();
    s = sb2[0] + sb2[1] + sb2[2] + sb2[3];
    m = fmaxf(fmaxf(sb2[4], sb2[5]), fmaxf(sb2[6], sb2[7]));
}

// ---------------- weight stats: mean|W| per weight ----------------
__global__ void wstats1(const float* __restrict__ w0, const float* __restrict__ w1,
                        const float* __restrict__ w2, const float* __restrict__ w3,
                        float* __restrict__ wpart) {
    int w = blockIdx.x >> 7;
    int slice = blockIdx.x & 127;
    const float* W = (w == 0) ? w0 : ((w == 1) ? w1 : ((w == 2) ? w2 : w3));
    const float4* p = (const float4*)(W + (size_t)slice * (WELEM / 128));
    float s = 0.f;
    for (int i = threadIdx.x; i < (WELEM / 128 / 4); i += 256) {
        float4 v = p[i];
        s += fabsf(v.x) + fabsf(v.y) + fabsf(v.z) + fabsf(v.w);
    }
    s = block_sum256(s);
    if (threadIdx.x == 0) wpart[blockIdx.x] = s;
}

__global__ void wstats2(const float* __restrict__ wpart, float* __restrict__ wdeq) {
    int w = threadIdx.x >> 6;
    int lane = threadIdx.x & 63;
    float s = wpart[w * 128 + lane] + wpart[w * 128 + 64 + lane];
#pragma unroll
    for (int off = 32; off > 0; off >>= 1) s += __shfl_down(s, off);
    if (lane == 0) wdeq[w] = fmaxf(s * (1.0f / (float)WELEM), 1e-5f);
}

// ---------------- merged: weight ternary quant (blocks 0..16383) + act quant ------
__global__ void quant_all(const float* __restrict__ w0, const float* __restrict__ w1,
                          const float* __restrict__ w2, const float* __restrict__ w3,
                          const float* __restrict__ wdeq, int8_t* __restrict__ wq,
                          const float* __restrict__ x, int8_t* __restrict__ xq,
                          float* __restrict__ adeq) {
    if (blockIdx.x < 16384) {
        // ----- weight ternary quantization: one float4 group per thread -----
        size_t idx = (size_t)blockIdx.x * 256 + threadIdx.x;
        int w = (int)(idx >> 20);                               // WELEM/4 = 2^20 groups/weight
        size_t g = idx & ((1u << 20) - 1);
        const float* W = (w == 0) ? w0 : ((w == 1) ? w1 : ((w == 2) ? w2 : w3));
        float inv = 1.0f / wdeq[w];                             // = ws
        float4 v = ((const float4*)W)[g];
        int q0 = (int)rintf(v.x * inv); q0 = q0 < -1 ? -1 : (q0 > 1 ? 1 : q0);
        int q1 = (int)rintf(v.y * inv); q1 = q1 < -1 ? -1 : (q1 > 1 ? 1 : q1);
        int q2 = (int)rintf(v.z * inv); q2 = q2 < -1 ? -1 : (q2 > 1 ? 1 : q2);
        int q3 = (int)rintf(v.w * inv); q3 = q3 < -1 ? -1 : (q3 > 1 ? 1 : q3);
        uint32_t p = (uint32_t)(q0 & 0xff) | ((uint32_t)(q1 & 0xff) << 8) |
                     ((uint32_t)(q2 & 0xff) << 16) | ((uint32_t)(q3 & 0xff) << 24);
        ((uint32_t*)(wq + (size_t)w * WELEM))[g] = p;
        return;
    }
    // ----- activation rmsnorm + int8 quant (one row per block) -----
    int row = blockIdx.x - 16384, tid = threadIdx.x;
    const float4* xr = (const float4*)(x + (size_t)row * D_DIM);
    float4 a = xr[2 * tid], b = xr[2 * tid + 1];
    float v[8] = {a.x, a.y, a.z, a.w, b.x, b.y, b.z, b.w};
    float ss = 0.f, mx = 0.f;
#pragma unroll
    for (int j = 0; j < 8; j++) { ss += v[j] * v[j]; mx = fmaxf(mx, fabsf(v[j])); }
    block_sum_max256(ss, mx);
    float inv = rsqrtf(ss * (1.0f / (float)D_DIM) + 1e-5f);
    float anc = fmaxf(mx * inv, 1e-5f);      // max|xn| clipped
    float s = 127.0f / anc;
    if (tid == 0) adeq[row] = anc * (1.0f / 127.0f);
    float sc = inv * s;
    int q[8];
#pragma unroll
    for (int j = 0; j < 8; j++) {
        int t = (int)rintf(v[j] * sc);
        q[j] = t < -128 ? -128 : (t > 127 ? 127 : t);
    }
    uint32_t lo = (uint32_t)(q[0] & 0xff) | ((uint32_t)(q[1] & 0xff) << 8) |
                  ((uint32_t)(q[2] & 0xff) << 16) | ((uint32_t)(q[3] & 0xff) << 24);
    uint32_t hi = (uint32_t)(q[4] & 0xff) | ((uint32_t)(q[5] & 0xff) << 8) |
                  ((uint32_t)(q[6] & 0xff) << 16) | ((uint32_t)(q[7] & 0xff) << 24);
    ((uint2*)(xq + (size_t)row * D_DIM))[tid] = make_uint2(lo, hi);
}

// ---------------- int8 x ternary GEMM core: 128x256 tile, BK=64B, 4 waves ---------
// Wave wv: wm=(wv&1)*64 (2 m-groups of 32), wn=(wv>>1)*128 (4 n-groups of 32).
// mfma_i32_32x32x32_i8: per K-iter, 2 k-steps x (2 m x 4 n) = 16 MFMA/wave.
//
//  - A operand loads DIRECTLY global->VGPR (4 dwordx4/wave/iter, per-lane
//    fragment addresses row=l&31, kchunk=l>>5).  Wave pairs read identical
//    A lines -> L1 dedups.  A never touches LDS.
//  - B in LDS via global_load_lds, fragment-order, double-buffered:
//    LDS/block = 2 x 16 KB = 32 KB.
//  - counted vmcnt(8) = 4 B-stages + 4 A-loads of the NEXT tile in flight;
//    never drains to 0 in the main loop.  2 raw barriers/iter.
//  - __launch_bounds__(256, 2): acc alone is 128 unified VGPRs/lane; a
//    3+ waves/EU budget forces a catastrophic accumulator spill (round-3
//    lesson: VGPR_Count=64, 10 GB of scratch traffic, 2% MfmaUtil).
#define BM 128
#define BN 256
#define BKB 64

#define MFMA32(a, b, c) __builtin_amdgcn_mfma_i32_32x32x32_i8((a), (b), (c), 0, 0, 0)

template <typename OutT>
__device__ __forceinline__ void gemm_core(
    const int8_t* __restrict__ A, const int8_t* __restrict__ Bw,
    const float* __restrict__ adeq, float wsc,
    int m0, int n0, OutT* __restrict__ Cout) {
    __shared__ __align__(16) int8_t sB[2][BN * BKB];   // 2 x 16 KB, 8 groups of 2KB
    int lane = threadIdx.x & 63;
    int wv = threadIdx.x >> 6;
    int wm = (wv & 1) * 64;          // wave's 2 A m-groups
    int wn = (wv >> 1) * 128;        // wave's 4 B n-groups
    int r32 = lane & 31;             // row within a 32-row group
    int h32 = lane >> 5;             // 16B k-chunk half selector

    const v16i vzero = {0, 0, 0, 0, 0, 0, 0, 0, 0, 0, 0, 0, 0, 0, 0, 0};
    v16i acc[2][4];
#pragma unroll
    for (int m = 0; m < 2; m++)
#pragma unroll
        for (int j = 0; j < 4; j++) acc[m][j] = vzero;

    // per-lane fragment base addresses (row = r32, k-chunk = h32)
    const int8_t* Adir = A + (size_t)(m0 + wm + r32) * K_DIM + h32 * 16;
    const int8_t* Bsrc = Bw + (size_t)(n0 + r32) * K_DIM + h32 * 16;
    const int bg = (wv >> 1) * 4;    // this wave's first B group

    // wave wv stages B groups 2wv, 2wv+1 (4 gl_lds = 4 KB)
#define STAGE_B(c, kt) do {                                                                      \
    gl_lds16(Bsrc + (size_t)((2 * wv) * 32) * K_DIM + (kt),          &sB[c][(2 * wv) * 2048]);          \
    gl_lds16(Bsrc + (size_t)((2 * wv) * 32) * K_DIM + (kt) + 32,     &sB[c][(2 * wv) * 2048 + 1024]);   \
    gl_lds16(Bsrc + (size_t)((2 * wv + 1) * 32) * K_DIM + (kt),      &sB[c][(2 * wv + 1) * 2048]);      \
    gl_lds16(Bsrc + (size_t)((2 * wv + 1) * 32) * K_DIM + (kt) + 32, &sB[c][(2 * wv + 1) * 2048 + 1024]); \
  } while (0)

    // A fragments for tile kt -> register set AC (4 x dwordx4)
#define LOAD_A(AC, kt) do {                                                       \
    _Pragma("unroll") for (int m_ = 0; m_ < 2; m_++)                              \
    _Pragma("unroll") for (int k_ = 0; k_ < 2; k_++)                              \
        AC[m_][k_] = *(const v4i*)(Adir + (size_t)(m_ * 32) * K_DIM + (kt) + k_ * 32); \
  } while (0)

    // one K-iter: consume buf c + regs AC for tile kt; prefetch tile kt+2*BKB
#define GBODY(c, AC, kt) do {                                                     \
    v4i bf[4][2];                                                                 \
    _Pragma("unroll") for (int j_ = 0; j_ < 4; j_++)                              \
    _Pragma("unroll") for (int k_ = 0; k_ < 2; k_++)                              \
        bf[j_][k_] = *(const v4i*)(&sB[c][(bg + j_) * 2048 + k_ * 1024 + lane * 16]); \
    __builtin_amdgcn_s_setprio(1);                                                \
    _Pragma("unroll") for (int j_ = 0; j_ < 4; j_++) {                            \
        acc[0][j_] = MFMA32(AC[0][0], bf[j_][0], acc[0][j_]);                     \
        acc[1][j_] = MFMA32(AC[1][0], bf[j_][0], acc[1][j_]);                     \
        acc[0][j_] = MFMA32(AC[0][1], bf[j_][1], acc[0][j_]);                     \
        acc[1][j_] = MFMA32(AC[1][1], bf[j_][1], acc[1][j_]);                     \
    }                                                                             \
    __builtin_amdgcn_s_setprio(0);                                                \
    wg_barrier();                 /* all waves done reading sB[c] */              \
    if ((kt) + 2 * BKB < K_DIM) { STAGE_B(c, (kt) + 2 * BKB); LOAD_A(AC, (kt) + 2 * BKB); } \
    if ((kt) + BKB < K_DIM) {                                                     \
        if ((kt) + 2 * BKB < K_DIM)                                               \
            asm volatile("s_waitcnt vmcnt(8)" ::: "memory");  /* tile kt+1 landed */ \
        else                                                                      \
            asm volatile("s_waitcnt vmcnt(0)" ::: "memory");                      \
        wg_barrier();                                                             \
    }                                                                             \
  } while (0)

    v4i a0[2][2], a1[2][2];
    STAGE_B(0, 0);      LOAD_A(a0, 0);        // tile 0
    STAGE_B(1, BKB);    LOAD_A(a1, BKB);      // tile 1
    asm volatile("s_waitcnt vmcnt(8)" ::: "memory");   // tile 0 landed, tile 1 in flight
    wg_barrier();

    for (int kt = 0; kt < K_DIM; kt += 2 * BKB) {
        GBODY(0, a0, kt);
        GBODY(1, a1, kt + BKB);
    }
#undef GBODY
#undef LOAD_A
#undef STAGE_B

    // C/D 32x32 layout: col = lane&31 (N/W side), row = (r&3)+8*(r>>2)+4*(lane>>5)
#pragma unroll
    for (int m = 0; m < 2; m++) {
#pragma unroll
        for (int r = 0; r < 16; r++) {
            int rr = (r & 3) + 8 * (r >> 2) + 4 * h32;
            int row = m0 + wm + m * 32 + rr;
            float rs = adeq[row] * wsc;
            OutT* crow = Cout + (size_t)row * N_DIM + n0 + wn + r32;
#pragma unroll
            for (int j = 0; j < 4; j++) store_out(crow + j * 32, (float)acc[m][j][r] * rs);
        }
    }
}

// merged i/f/g GEMM: grid.x = 24 (8 N-tiles x 3 weights), grid.y = 64 M-tiles
__global__ __launch_bounds__(256, 2) void gemm_ifg(
    const int8_t* __restrict__ xq, const int8_t* __restrict__ wq,
    const float* __restrict__ adeq, const float* __restrict__ wdeq,
    bfraw* __restrict__ bufI, bfraw* __restrict__ bufF, bfraw* __restrict__ bufG) {
    int widx = blockIdx.x >> 3;
    int n0 = (blockIdx.x & 7) * BN;
    int m0 = blockIdx.y * BM;
    bfraw* outp = (widx == 0) ? bufI : ((widx == 1) ? bufF : bufG);
    gemm_core<bfraw>(xq, wq + (size_t)widx * WELEM, adeq, wdeq[widx], m0, n0, outp);
}

// final o GEMM: fp32 out. grid.x = 8, grid.y = 64
__global__ __launch_bounds__(256, 2) void gemm_o(
    const int8_t* __restrict__ oq, const int8_t* __restrict__ wq,
    const float* __restrict__ odeq, const float* __restrict__ wdeq,
    float* __restrict__ out) {
    gemm_core<float>(oq, wq + 3 * (size_t)WELEM, odeq, wdeq[3], blockIdx.y * BM,
                     blockIdx.x * BN, out);
}

// ---------------- chunked scan with fused activations ----------------
// f_t = sigmoid(fL_t); i_t = silu(iL_t)*(1-f_t); h_t = f_t*h_{t-1} + i_t
__global__ void scan1(const bfraw* __restrict__ iL, const bfraw* __restrict__ fL,
                      float* __restrict__ Fc, float* __restrict__ Ic) {
    int idx = blockIdx.x * 256 + threadIdx.x;   // 4*64*2048
    int d = idx & (D_DIM - 1);
    int c = (idx >> 11) & (NCH - 1);
    int b = idx >> 17;
    size_t base = ((size_t)(b * L_DIM + c * CHUNK)) * D_DIM + d;
    float F = 1.f, h = 0.f;
#pragma unroll 4
    for (int t = 0; t < CHUNK; t++) {
        float fr = bf2f(fL[base + (size_t)t * D_DIM]);
        float ir = bf2f(iL[base + (size_t)t * D_DIM]);
        float fv = sigmoidf_(fr);
        float iv = ir * sigmoidf_(ir) * (1.0f - fv);
        h = fv * h + iv;
        F *= fv;
    }
    size_t ci = ((size_t)b * NCH + c) * D_DIM + d;
    Fc[ci] = F;
    Ic[ci] = h;
}

__global__ void scan2(const float* __restrict__ Fc, const float* __restrict__ Ic,
                      float* __restrict__ Hc) {
    int idx = blockIdx.x * 256 + threadIdx.x;   // 8192
    int d = idx & (D_DIM - 1);
    int b = idx >> 11;
    float h = 0.f;
    for (int c0 = 0; c0 < NCH; c0 += 8) {
        float F[8], I[8];
#pragma unroll
        for (int j = 0; j < 8; j++) {
            size_t ci = ((size_t)b * NCH + c0 + j) * D_DIM + d;
            F[j] = Fc[ci];
            I[j] = Ic[ci];
        }
#pragma unroll
        for (int j = 0; j < 8; j++) {
            size_t ci = ((size_t)b * NCH + c0 + j) * D_DIM + d;
            Hc[ci] = h;
            h = F[j] * h + I[j];
        }
    }
}

__global__ void scan3(const bfraw* __restrict__ iL, const bfraw* __restrict__ fL,
                      const float* __restrict__ Hc, bfraw* __restrict__ hout) {
    int idx = blockIdx.x * 256 + threadIdx.x;
    int d = idx & (D_DIM - 1);
    int c = (idx >> 11) & (NCH - 1);
    int b = idx >> 17;
    size_t base = ((size_t)(b * L_DIM + c * CHUNK)) * D_DIM + d;
    float h = Hc[((size_t)b * NCH + c) * D_DIM + d];
#pragma unroll 4
    for (int t = 0; t < CHUNK; t++) {
        size_t a = base + (size_t)t * D_DIM;
        float fr = bf2f(fL[a]);
        float ir = bf2f(iL[a]);
        float fv = sigmoidf_(fr);
        float iv = ir * sigmoidf_(ir) * (1.0f - fv);
        h = fv * h + iv;
        hout[a] = f2bf(h);
    }
}

// ---------------- g-path: o = rmsnorm(g)*gw * h*sigmoid(h); rmsnorm+quant o ---------
union BF8 { uint4 u; bfraw s[8]; };

__global__ void gout_quant(const bfraw* __restrict__ gL, const bfraw* __restrict__ h,
                           const float* __restrict__ gw, int8_t* __restrict__ oq,
                           float* __restrict__ odeq) {
    int row = blockIdx.x, tid = threadIdx.x;
    BF8 g8, h8;
    g8.u = ((const uint4*)(gL + (size_t)row * D_DIM))[tid];
    float gv[8];
    float ss = 0.f;
#pragma unroll
    for (int j = 0; j < 8; j++) { gv[j] = bf2f(g8.s[j]); ss += gv[j] * gv[j]; }
    float ssg = block_sum256(ss);
    float invg = rsqrtf(ssg * (1.0f / (float)D_DIM) + 1e-5f);

    h8.u = ((const uint4*)(h + (size_t)row * D_DIM))[tid];
    const float4* wr = (const float4*)gw;
    float4 w0 = wr[2 * tid], w1 = wr[2 * tid + 1];
    float wv[8] = {w0.x, w0.y, w0.z, w0.w, w1.x, w1.y, w1.z, w1.w};
    float o[8];
    float sso = 0.f, amax = 0.f;
#pragma unroll
    for (int j = 0; j < 8; j++) {
        float hv = bf2f(h8.s[j]);
        o[j] = gv[j] * invg * wv[j] * hv * sigmoidf_(hv);
        sso += o[j] * o[j];
        amax = fmaxf(amax, fabsf(o[j]));
    }
    block_sum_max256(sso, amax);
    float invo = rsqrtf(sso * (1.0f / (float)D_DIM) + 1e-5f);
    float anc = fmaxf(amax * invo, 1e-5f);
    float s = 127.0f / anc;
    if (tid == 0) odeq[row] = anc * (1.0f / 127.0f);
    float sc = invo * s;
    int q[8];
#pragma unroll
    for (int j = 0; j < 8; j++) {
        int t = (int)rintf(o[j] * sc);
        q[j] = t < -128 ? -128 : (t > 127 ? 127 : t);
    }
    uint32_t lo = (uint32_t)(q[0] & 0xff) | ((uint32_t)(q[1] & 0xff) << 8) |
                  ((uint32_t)(q[2] & 0xff) << 16) | ((uint32_t)(q[3] & 0xff) << 24);
    uint32_t hi = (uint32_t)(q[4] & 0xff) | ((uint32_t)(q[5] & 0xff) << 8) |
                  ((uint32_t)(q[6] & 0xff) << 16) | ((uint32_t)(q[7] & 0xff) << 24);
    ((uint2*)(oq + (size_t)row * D_DIM))[tid] = make_uint2(lo, hi);
}

// ---------------- driver ----------------
extern "C" void kernel_launch(void* const* d_in, const int* in_sizes, int n_in,
                              void* d_out, int out_size, void* d_ws, size_t ws_size,
                              hipStream_t stream) {
    const float* x  = (const float*)d_in[0];
    const float* Wi = (const float*)d_in[1];
    const float* Wf = (const float*)d_in[2];
    const float* Wg = (const float*)d_in[3];
    const float* Wo = (const float*)d_in[4];
    const float* gw = (const float*)d_in[5];
    float* out = (float*)d_out;

    char* ws = (char*)d_ws;
    float*  wdeq  = (float*)(ws + 0);                 // 4 floats
    float*  wpart = (float*)(ws + 256);               // 512 partials
    float*  adeq  = (float*)(ws + 0x10000);           // 8192 per-row act dequant
    float*  odeq  = (float*)(ws + 0x20000);           // 8192 per-row o dequant
    int8_t* xq    = (int8_t*)(ws + 0x100000);         // 16MB int8 x; reused as oq
    int8_t* wq    = (int8_t*)(ws + 0x1100000);        // 4 x 4MB ternary weights
    float*  Fc    = (float*)(ws + 0x2100000);         // 2MB chunk f-products
    float*  Ic    = (float*)(ws + 0x2300000);         // 2MB chunk partial h
    float*  Hc    = (float*)(ws + 0x2500000);         // 2MB chunk carries
    bfraw*  bufI  = (bfraw*)(ws + 0x4000000);         // 32MB bf16: i_lin
    bfraw*  bufF  = (bfraw*)(ws + 0x6000000);         // 32MB bf16: f_lin
    bfraw*  bufG  = (bfraw*)(ws + 0x8000000);         // 32MB bf16: g_lin
    bfraw*  hbuf  = (bfraw*)(ws + 0xA000000);         // 32MB bf16: h

    wstats1<<<512, 256, 0, stream>>>(Wi, Wf, Wg, Wo, wpart);
    wstats2<<<1, 256, 0, stream>>>(wpart, wdeq);
    quant_all<<<16384 + 8192, 256, 0, stream>>>(Wi, Wf, Wg, Wo, wdeq, wq, x, xq, adeq);

    gemm_ifg<<<dim3(24, M_DIM / BM), 256, 0, stream>>>(xq, wq, adeq, wdeq, bufI, bufF, bufG);

    scan1<<<2048, 256, 0, stream>>>(bufI, bufF, Fc, Ic);
    scan2<<<32, 256, 0, stream>>>(Fc, Ic, Hc);
    scan3<<<2048, 256, 0, stream>>>(bufI, bufF, Hc, hbuf);

    gout_quant<<<M_DIM, 256, 0, stream>>>(bufG, hbuf, gw, xq /*as oq*/, odeq);
    gemm_o<<<dim3(N_DIM / BN, M_DIM / BM), 256, 0, stream>>>(xq /*oq*/, wq, odeq, wdeq, out);

    (void)in_sizes; (void)n_in; (void)out_size; (void)ws_size;
}

// Round 5
// 454.734 us; speedup vs baseline: 6.2120x; 1.1797x over previous
//
#include <hip/hip_runtime.h>
#include <stdint.h>

// Problem constants (B=4, L=2048, D=2048)
#define B_DIM 4
#define L_DIM 2048
#define D_DIM 2048
#define M_DIM 8192              // B*L token rows
#define K_DIM 2048
#define N_DIM 2048
#define WELEM (D_DIM * D_DIM)   // 4194304 elements per weight
#define CHUNK 32
#define NCH (L_DIM / CHUNK)     // 64 chunks per sequence

typedef int v4i  __attribute__((ext_vector_type(4)));
typedef int v16i __attribute__((ext_vector_type(16)));
typedef unsigned short bfraw;   // bf16 bit pattern

#define AS1 __attribute__((address_space(1)))
#define AS3 __attribute__((address_space(3)))

__device__ __forceinline__ void gl_lds16(const void* g, void* l) {
    // async global->LDS, 16B per lane; LDS dst = wave-uniform base + lane*16
    __builtin_amdgcn_global_load_lds((AS1 void*)g, (AS3 void*)l, 16, 0, 0);
}

// raw workgroup barrier WITHOUT implicit vmcnt(0) drain (unlike __syncthreads)
__device__ __forceinline__ void wg_barrier() {
    asm volatile("" ::: "memory");
    __builtin_amdgcn_s_barrier();
    asm volatile("" ::: "memory");
}

__device__ __forceinline__ float sigmoidf_(float x) { return 1.0f / (1.0f + expf(-x)); }

__device__ __forceinline__ float bf2f(bfraw u) {
    union { unsigned int i; float f; } c; c.i = ((unsigned int)u) << 16; return c.f;
}
__device__ __forceinline__ bfraw f2bf(float f) {
    union { float f; unsigned int i; } c; c.f = f;
    unsigned int lsb = (c.i >> 16) & 1;
    c.i += 0x7fffu + lsb;                   // round-to-nearest-even
    return (bfraw)(c.i >> 16);
}

__device__ __forceinline__ void store_out(float* p, float v) { *p = v; }
__device__ __forceinline__ void store_out(bfraw* p, float v) { *p = f2bf(v); }

// ---------------- block reductions (256 threads = 4 waves) ----------------
__device__ __forceinline__ float block_sum256(float v) {
#pragma unroll
    for (int off = 32; off > 0; off >>= 1) v += __shfl_down(v, off);
    __shared__ float sb[4];
    int lane = threadIdx.x & 63, wv = threadIdx.x >> 6;
    __syncthreads();
    if (lane == 0) sb[wv] = v;
    __syncthreads();
    return sb[0] + sb[1] + sb[2] + sb[3];
}

__device__ __forceinline__ void block_sum_max256(float& s, float& m) {
#pragma unroll
    for (int off = 32; off > 0; off >>= 1) {
        s += __shfl_down(s, off);
        m = fmaxf(m, __shfl_down(m, off));
    }
    __shared__ float sb2[8];
    int lane = threadIdx.x & 63, wv = threadIdx.x >> 6;
    __syncthreads();
    if (lane == 0) { sb2[wv] = s; sb2[4 + wv] = m; }
    __syncthreads();
    s = sb2[0] + sb2[1] + sb2[2] + sb2[3];
    m = fmaxf(fmaxf(sb2[4], sb2[5]), fmaxf(sb2[6], sb2[7]));
}

// ---------------- weight stats: mean|W| per weight ----------------
__global__ void wstats1(const float* __restrict__ w0, const float* __restrict__ w1,
                        const float* __restrict__ w2, const float* __restrict__ w3,
                        float* __restrict__ wpart) {
    int w = blockIdx.x >> 7;
    int slice = blockIdx.x & 127;
    const float* W = (w == 0) ? w0 : ((w == 1) ? w1 : ((w == 2) ? w2 : w3));
    const float4* p = (const float4*)(W + (size_t)slice * (WELEM / 128));
    float s = 0.f;
    for (int i = threadIdx.x; i < (WELEM / 128 / 4); i += 256) {
        float4 v = p[i];
        s += fabsf(v.x) + fabsf(v.y) + fabsf(v.z) + fabsf(v.w);
    }
    s = block_sum256(s);
    if (threadIdx.x == 0) wpart[blockIdx.x] = s;
}

__global__ void wstats2(const float* __restrict__ wpart, float* __restrict__ wdeq) {
    int w = threadIdx.x >> 6;
    int lane = threadIdx.x & 63;
    float s = wpart[w * 128 + lane] + wpart[w * 128 + 64 + lane];
#pragma unroll
    for (int off = 32; off > 0; off >>= 1) s += __shfl_down(s, off);
    if (lane == 0) wdeq[w] = fmaxf(s * (1.0f / (float)WELEM), 1e-5f);
}

// ---------------- merged: weight ternary quant (blocks 0..16383) + act quant ------
__global__ void quant_all(const float* __restrict__ w0, const float* __restrict__ w1,
                          const float* __restrict__ w2, const float* __restrict__ w3,
                          const float* __restrict__ wdeq, int8_t* __restrict__ wq,
                          const float* __restrict__ x, int8_t* __restrict__ xq,
                          float* __restrict__ adeq) {
    if (blockIdx.x < 16384) {
        // ----- weight ternary quantization: one float4 group per thread -----
        size_t idx = (size_t)blockIdx.x * 256 + threadIdx.x;
        int w = (int)(idx >> 20);                               // WELEM/4 = 2^20 groups/weight
        size_t g = idx & ((1u << 20) - 1);
        const float* W = (w == 0) ? w0 : ((w == 1) ? w1 : ((w == 2) ? w2 : w3));
        float inv = 1.0f / wdeq[w];                             // = ws
        float4 v = ((const float4*)W)[g];
        int q0 = (int)rintf(v.x * inv); q0 = q0 < -1 ? -1 : (q0 > 1 ? 1 : q0);
        int q1 = (int)rintf(v.y * inv); q1 = q1 < -1 ? -1 : (q1 > 1 ? 1 : q1);
        int q2 = (int)rintf(v.z * inv); q2 = q2 < -1 ? -1 : (q2 > 1 ? 1 : q2);
        int q3 = (int)rintf(v.w * inv); q3 = q3 < -1 ? -1 : (q3 > 1 ? 1 : q3);
        uint32_t p = (uint32_t)(q0 & 0xff) | ((uint32_t)(q1 & 0xff) << 8) |
                     ((uint32_t)(q2 & 0xff) << 16) | ((uint32_t)(q3 & 0xff) << 24);
        ((uint32_t*)(wq + (size_t)w * WELEM))[g] = p;
        return;
    }
    // ----- activation rmsnorm + int8 quant (one row per block) -----
    int row = blockIdx.x - 16384, tid = threadIdx.x;
    const float4* xr = (const float4*)(x + (size_t)row * D_DIM);
    float4 a = xr[2 * tid], b = xr[2 * tid + 1];
    float v[8] = {a.x, a.y, a.z, a.w, b.x, b.y, b.z, b.w};
    float ss = 0.f, mx = 0.f;
#pragma unroll
    for (int j = 0; j < 8; j++) { ss += v[j] * v[j]; mx = fmaxf(mx, fabsf(v[j])); }
    block_sum_max256(ss, mx);
    float inv = rsqrtf(ss * (1.0f / (float)D_DIM) + 1e-5f);
    float anc = fmaxf(mx * inv, 1e-5f);      // max|xn| clipped
    float s = 127.0f / anc;
    if (tid == 0) adeq[row] = anc * (1.0f / 127.0f);
    float sc = inv * s;
    int q[8];
#pragma unroll
    for (int j = 0; j < 8; j++) {
        int t = (int)rintf(v[j] * sc);
        q[j] = t < -128 ? -128 : (t > 127 ? 127 : t);
    }
    uint32_t lo = (uint32_t)(q[0] & 0xff) | ((uint32_t)(q[1] & 0xff) << 8) |
                  ((uint32_t)(q[2] & 0xff) << 16) | ((uint32_t)(q[3] & 0xff) << 24);
    uint32_t hi = (uint32_t)(q[4] & 0xff) | ((uint32_t)(q[5] & 0xff) << 8) |
                  ((uint32_t)(q[6] & 0xff) << 16) | ((uint32_t)(q[7] & 0xff) << 24);
    ((uint2*)(xq + (size_t)row * D_DIM))[tid] = make_uint2(lo, hi);
}

// ---------------- int8 x ternary GEMM: 256x256 tile, 8 waves, 8-phase schedule ----
// Port of the verified 256^2 8-phase template (m196->m201) to i8 32x32x32.
// Wave wv: wr=wv>>2 (2 M-rows), wc=wv&3 (4 N-cols) -> per-wave 128x64 output:
//   4 m-tiles (A groups ag..ag+3, ag=wr*4) x 2 n-tiles (B groups bg,bg+1, bg=wc*2),
//   acc = 8 x v16i = 128 unified VGPRs.
// K-tile = 64 B.  LDS: 3-deep ring x (16KB A + 16KB B) = 96 KB, fragment-order
// linear per 32-row group (2KB = 2 k-slices x 1KB; lane l at byte l*16 holds
// row=l&31, kbyte=slice*32+(l>>5)*16) -> ds_read_b128 = linear 1KB wave read,
// 0 bank conflicts.  Staged via per-lane pre-permuted global src (rule 21).
// Schedule per K-tile t (2 phases, template form):
//   P0: ds_read A-half0(4)+B(4); stage s0 of tile t+2; barrier; lgkmcnt(0);
//       setprio(1); 8 MFMA; setprio(0); barrier.
//   P1: ds_read A-half1(4); stage s1 of tile t+2; vmcnt(4) [tile t+1 landed,
//       t+2's 4 loads stay in flight -- never 0 mid-loop]; barrier; lgkmcnt(0);
//       setprio(1); 8 MFMA; setprio(0); barrier.
// __launch_bounds__(512,2): 256-reg/wave budget (acc alone is 128; a higher
// wave target spills the accumulator -- round-3 lesson: 10 GB scratch, 2% util).
#define BM2 256
#define BN2 256
#define BKB 64
#define NT (K_DIM / BKB)        // 32 K-tiles

#define MFMA32(a, b, c) __builtin_amdgcn_mfma_i32_32x32x32_i8((a), (b), (c), 0, 0, 0)

template <typename OutT>
__device__ __forceinline__ void gemm_core(
    const int8_t* __restrict__ A, const int8_t* __restrict__ Bw,
    const float* __restrict__ adeq, float wsc,
    int m0, int n0, OutT* __restrict__ Cout) {
    __shared__ __align__(16) int8_t sA[3][BM2 * BKB];   // 3 x 16 KB
    __shared__ __align__(16) int8_t sB[3][BN2 * BKB];   // 3 x 16 KB
    int lane = threadIdx.x & 63;
    int wv = threadIdx.x >> 6;       // 0..7
    int wr = wv >> 2, wc = wv & 3;
    int r32 = lane & 31;             // row within a 32-row group
    int h32 = lane >> 5;             // 16B chunk within a 32B k-slice
    const int ag = wr * 4;           // first A group (of 8)
    const int bg = wc * 2;           // first B group (of 8)
    const int lb = lane * 16;        // linear frag byte offset

    const v16i vzero = {0, 0, 0, 0, 0, 0, 0, 0, 0, 0, 0, 0, 0, 0, 0, 0};
    v16i acc[4][2];
#pragma unroll
    for (int m = 0; m < 4; m++)
#pragma unroll
        for (int n = 0; n < 2; n++) acc[m][n] = vzero;

    // per-lane pre-permuted global source base (row = r32, 16B chunk = h32)
    const int8_t* Asrc = A + (size_t)(m0 + r32) * K_DIM + h32 * 16;
    const int8_t* Bsrc = Bw + (size_t)(n0 + r32) * K_DIM + h32 * 16;

    // wave wv stages A group wv + B group wv, k-slice s (2 gl_lds = 2 KB)
#define STG(c, kt, s) do {                                                                  \
    gl_lds16(Asrc + (size_t)(wv * 32) * K_DIM + (kt) + (s) * 32, &sA[c][wv * 2048 + (s) * 1024]); \
    gl_lds16(Bsrc + (size_t)(wv * 32) * K_DIM + (kt) + (s) * 32, &sB[c][wv * 2048 + (s) * 1024]); \
  } while (0)

#define LDF(buf, grp, s) (*(const v4i*)(&(buf)[(grp) * 2048 + (s) * 1024 + lb]))

    // prologue: tiles 0 and 1 (4 loads each)
    STG(0, 0, 0);   STG(0, 0, 1);
    STG(1, BKB, 0); STG(1, BKB, 1);
    asm volatile("s_waitcnt vmcnt(4)" ::: "memory");   // tile 0 landed, tile 1 in flight
    wg_barrier();

    int cur = 0;
    for (int t = 0; t < NT; ++t) {
        const int8_t* bA = &sA[cur][0];
        const int8_t* bB = &sB[cur][0];
        int c2 = cur + 2; if (c2 >= 3) c2 -= 3;
        int kt2 = (t + 2) * BKB;

        // ---------------- phase 0: A-half0 x B ----------------
        v4i a0s0 = LDF(bA, ag + 0, 0), a0s1 = LDF(bA, ag + 0, 1);
        v4i a1s0 = LDF(bA, ag + 1, 0), a1s1 = LDF(bA, ag + 1, 1);
        v4i b0s0 = LDF(bB, bg + 0, 0), b0s1 = LDF(bB, bg + 0, 1);
        v4i b1s0 = LDF(bB, bg + 1, 0), b1s1 = LDF(bB, bg + 1, 1);
        if (t + 2 < NT) STG(c2, kt2, 0);
        wg_barrier();
        asm volatile("s_waitcnt lgkmcnt(0)" ::: "memory");
        __builtin_amdgcn_sched_barrier(0);
        __builtin_amdgcn_s_setprio(1);
        acc[0][0] = MFMA32(a0s0, b0s0, acc[0][0]);
        acc[1][0] = MFMA32(a1s0, b0s0, acc[1][0]);
        acc[0][1] = MFMA32(a0s0, b1s0, acc[0][1]);
        acc[1][1] = MFMA32(a1s0, b1s0, acc[1][1]);
        acc[0][0] = MFMA32(a0s1, b0s1, acc[0][0]);
        acc[1][0] = MFMA32(a1s1, b0s1, acc[1][0]);
        acc[0][1] = MFMA32(a0s1, b1s1, acc[0][1]);
        acc[1][1] = MFMA32(a1s1, b1s1, acc[1][1]);
        __builtin_amdgcn_s_setprio(0);
        wg_barrier();

        // ---------------- phase 1: A-half1 x B ----------------
        v4i a2s0 = LDF(bA, ag + 2, 0), a2s1 = LDF(bA, ag + 2, 1);
        v4i a3s0 = LDF(bA, ag + 3, 0), a3s1 = LDF(bA, ag + 3, 1);
        if (t + 2 < NT) {
            STG(c2, kt2, 1);
            asm volatile("s_waitcnt vmcnt(4)" ::: "memory");   // tile t+1 landed; t+2 in flight
        } else if (t + 1 < NT) {
            asm volatile("s_waitcnt vmcnt(0)" ::: "memory");   // drain final tile's loads
        }
        wg_barrier();
        asm volatile("s_waitcnt lgkmcnt(0)" ::: "memory");
        __builtin_amdgcn_sched_barrier(0);
        __builtin_amdgcn_s_setprio(1);
        acc[2][0] = MFMA32(a2s0, b0s0, acc[2][0]);
        acc[3][0] = MFMA32(a3s0, b0s0, acc[3][0]);
        acc[2][1] = MFMA32(a2s0, b1s0, acc[2][1]);
        acc[3][1] = MFMA32(a3s0, b1s0, acc[3][1]);
        acc[2][0] = MFMA32(a2s1, b0s1, acc[2][0]);
        acc[3][0] = MFMA32(a3s1, b0s1, acc[3][0]);
        acc[2][1] = MFMA32(a2s1, b1s1, acc[2][1]);
        acc[3][1] = MFMA32(a3s1, b1s1, acc[3][1]);
        __builtin_amdgcn_s_setprio(0);
        wg_barrier();

        cur = cur + 1; if (cur >= 3) cur = 0;
    }
#undef LDF
#undef STG

    // C/D 32x32 layout: col = lane&31, row = (r&3)+8*(r>>2)+4*(lane>>5)
#pragma unroll
    for (int m = 0; m < 4; m++) {
#pragma unroll
        for (int r = 0; r < 16; r++) {
            int rr = (r & 3) + 8 * (r >> 2) + 4 * h32;
            int row = m0 + (ag + m) * 32 + rr;
            float rs = adeq[row] * wsc;
            OutT* crow = Cout + (size_t)row * N_DIM + n0 + bg * 32 + r32;
            store_out(crow,      (float)acc[m][0][r] * rs);
            store_out(crow + 32, (float)acc[m][1][r] * rs);
        }
    }
}

// merged i/f/g GEMM: grid.x = 24 (8 N-tiles x 3 weights), grid.y = 32 M-tiles
__global__ __launch_bounds__(512, 2) void gemm_ifg(
    const int8_t* __restrict__ xq, const int8_t* __restrict__ wq,
    const float* __restrict__ adeq, const float* __restrict__ wdeq,
    bfraw* __restrict__ bufI, bfraw* __restrict__ bufF, bfraw* __restrict__ bufG) {
    int widx = blockIdx.x >> 3;
    int n0 = (blockIdx.x & 7) * BN2;
    int m0 = blockIdx.y * BM2;
    bfraw* outp = (widx == 0) ? bufI : ((widx == 1) ? bufF : bufG);
    gemm_core<bfraw>(xq, wq + (size_t)widx * WELEM, adeq, wdeq[widx], m0, n0, outp);
}

// final o GEMM: fp32 out. grid.x = 8, grid.y = 32
__global__ __launch_bounds__(512, 2) void gemm_o(
    const int8_t* __restrict__ oq, const int8_t* __restrict__ wq,
    const float* __restrict__ odeq, const float* __restrict__ wdeq,
    float* __restrict__ out) {
    gemm_core<float>(oq, wq + 3 * (size_t)WELEM, odeq, wdeq[3], blockIdx.y * BM2,
                     blockIdx.x * BN2, out);
}

// ---------------- chunked scan with fused activations ----------------
// f_t = sigmoid(fL_t); i_t = silu(iL_t)*(1-f_t); h_t = f_t*h_{t-1} + i_t
__global__ void scan1(const bfraw* __restrict__ iL, const bfraw* __restrict__ fL,
                      float* __restrict__ Fc, float* __restrict__ Ic) {
    int idx = blockIdx.x * 256 + threadIdx.x;   // 4*64*2048
    int d = idx & (D_DIM - 1);
    int c = (idx >> 11) & (NCH - 1);
    int b = idx >> 17;
    size_t base = ((size_t)(b * L_DIM + c * CHUNK)) * D_DIM + d;
    float F = 1.f, h = 0.f;
#pragma unroll 4
    for (int t = 0; t < CHUNK; t++) {
        float fr = bf2f(fL[base + (size_t)t * D_DIM]);
        float ir = bf2f(iL[base + (size_t)t * D_DIM]);
        float fv = sigmoidf_(fr);
        float iv = ir * sigmoidf_(ir) * (1.0f - fv);
        h = fv * h + iv;
        F *= fv;
    }
    size_t ci = ((size_t)b * NCH + c) * D_DIM + d;
    Fc[ci] = F;
    Ic[ci] = h;
}

__global__ void scan2(const float* __restrict__ Fc, const float* __restrict__ Ic,
                      float* __restrict__ Hc) {
    int idx = blockIdx.x * 256 + threadIdx.x;   // 8192
    int d = idx & (D_DIM - 1);
    int b = idx >> 11;
    float h = 0.f;
    for (int c0 = 0; c0 < NCH; c0 += 8) {
        float F[8], I[8];
#pragma unroll
        for (int j = 0; j < 8; j++) {
            size_t ci = ((size_t)b * NCH + c0 + j) * D_DIM + d;
            F[j] = Fc[ci];
            I[j] = Ic[ci];
        }
#pragma unroll
        for (int j = 0; j < 8; j++) {
            size_t ci = ((size_t)b * NCH + c0 + j) * D_DIM + d;
            Hc[ci] = h;
            h = F[j] * h + I[j];
        }
    }
}

__global__ void scan3(const bfraw* __restrict__ iL, const bfraw* __restrict__ fL,
                      const float* __restrict__ Hc, bfraw* __restrict__ hout) {
    int idx = blockIdx.x * 256 + threadIdx.x;
    int d = idx & (D_DIM - 1);
    int c = (idx >> 11) & (NCH - 1);
    int b = idx >> 17;
    size_t base = ((size_t)(b * L_DIM + c * CHUNK)) * D_DIM + d;
    float h = Hc[((size_t)b * NCH + c) * D_DIM + d];
#pragma unroll 4
    for (int t = 0; t < CHUNK; t++) {
        size_t a = base + (size_t)t * D_DIM;
        float fr = bf2f(fL[a]);
        float ir = bf2f(iL[a]);
        float fv = sigmoidf_(fr);
        float iv = ir * sigmoidf_(ir) * (1.0f - fv);
        h = fv * h + iv;
        hout[a] = f2bf(h);
    }
}

// ---------------- g-path: o = rmsnorm(g)*gw * h*sigmoid(h); rmsnorm+quant o ---------
union BF8 { uint4 u; bfraw s[8]; };

__global__ void gout_quant(const bfraw* __restrict__ gL, const bfraw* __restrict__ h,
                           const float* __restrict__ gw, int8_t* __restrict__ oq,
                           float* __restrict__ odeq) {
    int row = blockIdx.x, tid = threadIdx.x;
    BF8 g8, h8;
    g8.u = ((const uint4*)(gL + (size_t)row * D_DIM))[tid];
    float gv[8];
    float ss = 0.f;
#pragma unroll
    for (int j = 0; j < 8; j++) { gv[j] = bf2f(g8.s[j]); ss += gv[j] * gv[j]; }
    float ssg = block_sum256(ss);
    float invg = rsqrtf(ssg * (1.0f / (float)D_DIM) + 1e-5f);

    h8.u = ((const uint4*)(h + (size_t)row * D_DIM))[tid];
    const float4* wr = (const float4*)gw;
    float4 w0 = wr[2 * tid], w1 = wr[2 * tid + 1];
    float wv[8] = {w0.x, w0.y, w0.z, w0.w, w1.x, w1.y, w1.z, w1.w};
    float o[8];
    float sso = 0.f, amax = 0.f;
#pragma unroll
    for (int j = 0; j < 8; j++) {
        float hv = bf2f(h8.s[j]);
        o[j] = gv[j] * invg * wv[j] * hv * sigmoidf_(hv);
        sso += o[j] * o[j];
        amax = fmaxf(amax, fabsf(o[j]));
    }
    block_sum_max256(sso, amax);
    float invo = rsqrtf(sso * (1.0f / (float)D_DIM) + 1e-5f);
    float anc = fmaxf(amax * invo, 1e-5f);
    float s = 127.0f / anc;
    if (tid == 0) odeq[row] = anc * (1.0f / 127.0f);
    float sc = invo * s;
    int q[8];
#pragma unroll
    for (int j = 0; j < 8; j++) {
        int t = (int)rintf(o[j] * sc);
        q[j] = t < -128 ? -128 : (t > 127 ? 127 : t);
    }
    uint32_t lo = (uint32_t)(q[0] & 0xff) | ((uint32_t)(q[1] & 0xff) << 8) |
                  ((uint32_t)(q[2] & 0xff) << 16) | ((uint32_t)(q[3] & 0xff) << 24);
    uint32_t hi = (uint32_t)(q[4] & 0xff) | ((uint32_t)(q[5] & 0xff) << 8) |
                  ((uint32_t)(q[6] & 0xff) << 16) | ((uint32_t)(q[7] & 0xff) << 24);
    ((uint2*)(oq + (size_t)row * D_DIM))[tid] = make_uint2(lo, hi);
}

// ---------------- driver ----------------
extern "C" void kernel_launch(void* const* d_in, const int* in_sizes, int n_in,
                              void* d_out, int out_size, void* d_ws, size_t ws_size,
                              hipStream_t stream) {
    const float* x  = (const float*)d_in[0];
    const float* Wi = (const float*)d_in[1];
    const float* Wf = (const float*)d_in[2];
    const float* Wg = (const float*)d_in[3];
    const float* Wo = (const float*)d_in[4];
    const float* gw = (const float*)d_in[5];
    float* out = (float*)d_out;

    char* ws = (char*)d_ws;
    float*  wdeq  = (float*)(ws + 0);                 // 4 floats
    float*  wpart = (float*)(ws + 256);               // 512 partials
    float*  adeq  = (float*)(ws + 0x10000);           // 8192 per-row act dequant
    float*  odeq  = (float*)(ws + 0x20000);           // 8192 per-row o dequant
    int8_t* xq    = (int8_t*)(ws + 0x100000);         // 16MB int8 x; reused as oq
    int8_t* wq    = (int8_t*)(ws + 0x1100000);        // 4 x 4MB ternary weights
    float*  Fc    = (float*)(ws + 0x2100000);         // 2MB chunk f-products
    float*  Ic    = (float*)(ws + 0x2300000);         // 2MB chunk partial h
    float*  Hc    = (float*)(ws + 0x2500000);         // 2MB chunk carries
    bfraw*  bufI  = (bfraw*)(ws + 0x4000000);         // 32MB bf16: i_lin
    bfraw*  bufF  = (bfraw*)(ws + 0x6000000);         // 32MB bf16: f_lin
    bfraw*  bufG  = (bfraw*)(ws + 0x8000000);         // 32MB bf16: g_lin
    bfraw*  hbuf  = (bfraw*)(ws + 0xA000000);         // 32MB bf16: h

    wstats1<<<512, 256, 0, stream>>>(Wi, Wf, Wg, Wo, wpart);
    wstats2<<<1, 256, 0, stream>>>(wpart, wdeq);
    quant_all<<<16384 + 8192, 256, 0, stream>>>(Wi, Wf, Wg, Wo, wdeq, wq, x, xq, adeq);

    gemm_ifg<<<dim3(24, M_DIM / BM2), 512, 0, stream>>>(xq, wq, adeq, wdeq, bufI, bufF, bufG);

    scan1<<<2048, 256, 0, stream>>>(bufI, bufF, Fc, Ic);
    scan2<<<32, 256, 0, stream>>>(Fc, Ic, Hc);
    scan3<<<2048, 256, 0, stream>>>(bufI, bufF, Hc, hbuf);

    gout_quant<<<M_DIM, 256, 0, stream>>>(bufG, hbuf, gw, xq /*as oq*/, odeq);
    gemm_o<<<dim3(N_DIM / BN2, M_DIM / BM2), 512, 0, stream>>>(xq /*oq*/, wq, odeq, wdeq, out);

    (void)in_sizes; (void)n_in; (void)out_size; (void)ws_size;
}

// Round 6
// 418.725 us; speedup vs baseline: 6.7462x; 1.0860x over previous
//
#include <hip/hip_runtime.h>
#include <stdint.h>

// Problem constants (B=4, L=2048, D=2048)
#define B_DIM 4
#define L_DIM 2048
#define D_DIM 2048
#define M_DIM 8192              // B*L token rows
#define K_DIM 2048
#define N_DIM 2048
#define WELEM (D_DIM * D_DIM)   // 4194304 elements per weight
#define CHUNK 32
#define NCH (L_DIM / CHUNK)     // 64 chunks per sequence

typedef int v4i  __attribute__((ext_vector_type(4)));
typedef int v16i __attribute__((ext_vector_type(16)));
typedef unsigned short bfraw;   // bf16 bit pattern

#define AS1 __attribute__((address_space(1)))
#define AS3 __attribute__((address_space(3)))

__device__ __forceinline__ void gl_lds16(const void* g, void* l) {
    // async global->LDS, 16B per lane; LDS dst = wave-uniform base + lane*16
    __builtin_amdgcn_global_load_lds((AS1 void*)g, (AS3 void*)l, 16, 0, 0);
}

// raw workgroup barrier WITHOUT implicit vmcnt(0) drain (unlike __syncthreads)
__device__ __forceinline__ void wg_barrier() {
    asm volatile("" ::: "memory");
    __builtin_amdgcn_s_barrier();
    asm volatile("" ::: "memory");
}

__device__ __forceinline__ float sigmoidf_(float x) { return 1.0f / (1.0f + expf(-x)); }

__device__ __forceinline__ float bf2f(bfraw u) {
    union { unsigned int i; float f; } c; c.i = ((unsigned int)u) << 16; return c.f;
}
__device__ __forceinline__ bfraw f2bf(float f) {
    union { float f; unsigned int i; } c; c.f = f;
    unsigned int lsb = (c.i >> 16) & 1;
    c.i += 0x7fffu + lsb;                   // round-to-nearest-even
    return (bfraw)(c.i >> 16);
}

__device__ __forceinline__ void store_out(float* p, float v) { *p = v; }
__device__ __forceinline__ void store_out(bfraw* p, float v) { *p = f2bf(v); }

// ---------------- block reductions (256 threads = 4 waves) ----------------
__device__ __forceinline__ float block_sum256(float v) {
#pragma unroll
    for (int off = 32; off > 0; off >>= 1) v += __shfl_down(v, off);
    __shared__ float sb[4];
    int lane = threadIdx.x & 63, wv = threadIdx.x >> 6;
    __syncthreads();
    if (lane == 0) sb[wv] = v;
    __syncthreads();
    return sb[0] + sb[1] + sb[2] + sb[3];
}

__device__ __forceinline__ void block_sum_max256(float& s, float& m) {
#pragma unroll
    for (int off = 32; off > 0; off >>= 1) {
        s += __shfl_down(s, off);
        m = fmaxf(m, __shfl_down(m, off));
    }
    __shared__ float sb2[8];
    int lane = threadIdx.x & 63, wv = threadIdx.x >> 6;
    __syncthreads();
    if (lane == 0) { sb2[wv] = s; sb2[4 + wv] = m; }
    __syncthreads();
    s = sb2[0] + sb2[1] + sb2[2] + sb2[3];
    m = fmaxf(fmaxf(sb2[4], sb2[5]), fmaxf(sb2[6], sb2[7]));
}

// ---------------- weight stats: mean|W| per weight ----------------
__global__ void wstats1(const float* __restrict__ w0, const float* __restrict__ w1,
                        const float* __restrict__ w2, const float* __restrict__ w3,
                        float* __restrict__ wpart) {
    int w = blockIdx.x >> 7;
    int slice = blockIdx.x & 127;
    const float* W = (w == 0) ? w0 : ((w == 1) ? w1 : ((w == 2) ? w2 : w3));
    const float4* p = (const float4*)(W + (size_t)slice * (WELEM / 128));
    float s = 0.f;
    for (int i = threadIdx.x; i < (WELEM / 128 / 4); i += 256) {
        float4 v = p[i];
        s += fabsf(v.x) + fabsf(v.y) + fabsf(v.z) + fabsf(v.w);
    }
    s = block_sum256(s);
    if (threadIdx.x == 0) wpart[blockIdx.x] = s;
}

__global__ void wstats2(const float* __restrict__ wpart, float* __restrict__ wdeq) {
    int w = threadIdx.x >> 6;
    int lane = threadIdx.x & 63;
    float s = wpart[w * 128 + lane] + wpart[w * 128 + 64 + lane];
#pragma unroll
    for (int off = 32; off > 0; off >>= 1) s += __shfl_down(s, off);
    if (lane == 0) wdeq[w] = fmaxf(s * (1.0f / (float)WELEM), 1e-5f);
}

// ---------------- merged: weight ternary quant (blocks 0..16383) + act quant ------
__global__ void quant_all(const float* __restrict__ w0, const float* __restrict__ w1,
                          const float* __restrict__ w2, const float* __restrict__ w3,
                          const float* __restrict__ wdeq, int8_t* __restrict__ wq,
                          const float* __restrict__ x, int8_t* __restrict__ xq,
                          float* __restrict__ adeq) {
    if (blockIdx.x < 16384) {
        // ----- weight ternary quantization: one float4 group per thread -----
        size_t idx = (size_t)blockIdx.x * 256 + threadIdx.x;
        int w = (int)(idx >> 20);                               // WELEM/4 = 2^20 groups/weight
        size_t g = idx & ((1u << 20) - 1);
        const float* W = (w == 0) ? w0 : ((w == 1) ? w1 : ((w == 2) ? w2 : w3));
        float inv = 1.0f / wdeq[w];                             // = ws
        float4 v = ((const float4*)W)[g];
        int q0 = (int)rintf(v.x * inv); q0 = q0 < -1 ? -1 : (q0 > 1 ? 1 : q0);
        int q1 = (int)rintf(v.y * inv); q1 = q1 < -1 ? -1 : (q1 > 1 ? 1 : q1);
        int q2 = (int)rintf(v.z * inv); q2 = q2 < -1 ? -1 : (q2 > 1 ? 1 : q2);
        int q3 = (int)rintf(v.w * inv); q3 = q3 < -1 ? -1 : (q3 > 1 ? 1 : q3);
        uint32_t p = (uint32_t)(q0 & 0xff) | ((uint32_t)(q1 & 0xff) << 8) |
                     ((uint32_t)(q2 & 0xff) << 16) | ((uint32_t)(q3 & 0xff) << 24);
        ((uint32_t*)(wq + (size_t)w * WELEM))[g] = p;
        return;
    }
    // ----- activation rmsnorm + int8 quant (one row per block) -----
    int row = blockIdx.x - 16384, tid = threadIdx.x;
    const float4* xr = (const float4*)(x + (size_t)row * D_DIM);
    float4 a = xr[2 * tid], b = xr[2 * tid + 1];
    float v[8] = {a.x, a.y, a.z, a.w, b.x, b.y, b.z, b.w};
    float ss = 0.f, mx = 0.f;
#pragma unroll
    for (int j = 0; j < 8; j++) { ss += v[j] * v[j]; mx = fmaxf(mx, fabsf(v[j])); }
    block_sum_max256(ss, mx);
    float inv = rsqrtf(ss * (1.0f / (float)D_DIM) + 1e-5f);
    float anc = fmaxf(mx * inv, 1e-5f);      // max|xn| clipped
    float s = 127.0f / anc;
    if (tid == 0) adeq[row] = anc * (1.0f / 127.0f);
    float sc = inv * s;
    int q[8];
#pragma unroll
    for (int j = 0; j < 8; j++) {
        int t = (int)rintf(v[j] * sc);
        q[j] = t < -128 ? -128 : (t > 127 ? 127 : t);
    }
    uint32_t lo = (uint32_t)(q[0] & 0xff) | ((uint32_t)(q[1] & 0xff) << 8) |
                  ((uint32_t)(q[2] & 0xff) << 16) | ((uint32_t)(q[3] & 0xff) << 24);
    uint32_t hi = (uint32_t)(q[4] & 0xff) | ((uint32_t)(q[5] & 0xff) << 8) |
                  ((uint32_t)(q[6] & 0xff) << 16) | ((uint32_t)(q[7] & 0xff) << 24);
    ((uint2*)(xq + (size_t)row * D_DIM))[tid] = make_uint2(lo, hi);
}

// ---------------- int8 x ternary GEMM: 256x256 tile, 8 waves, 1-barrier regions ---
// Wave wv: wr=wv>>2, wc=wv&3 -> per-wave 128x64 output: 4 m-tiles x 2 n-tiles of
// 32x32, acc = 8 x v16i = 128 unified VGPRs.  K-tile = 64 B.
//
// LDS: 4-deep ring x (16KB A + 16KB B) = 128 KB, fragment-order linear per
// 32-row group (lane l at byte l*16 holds row=l&31, kchunk=l>>5) -> ds_read_b128
// is a linear 1KB wave read, 0 bank conflicts.  Staged via per-lane pre-permuted
// global source (rule 21).
//
// Schedule (r6): ONE region per K-tile = {12 ds_reads; STG(t+2) (4 gl_lds);
// 16 MFMA with setprio; vmcnt(4); barrier}.  No manual lgkmcnt / sched_barrier:
// the ds_reads are plain HIP loads, so the compiler emits fine-grained
// lgkmcnt(N) interleave and the LDS drain overlaps the MFMA cluster (r5's
// per-phase lgkmcnt(0)+sched_barrier(0) pinning made LDS and matrix pipes
// additive: 30% MfmaUtil).  vmcnt(4) at region t = tile t+1's 4 loads landed,
// tile t+2's stay in flight (never 0 mid-loop).  Ring-4 race audit: STG
// targets (t+2)&3 = buffer consumed at t-2, retired >=2 barriers ago for all
// waves -> single barrier per region is sufficient.
// __launch_bounds__(512,2): acc alone is 128 regs/lane; a higher wave target
// spills the accumulator (round-3 lesson: 10 GB scratch traffic, 2% util).
#define BM2 256
#define BN2 256
#define BKB 64
#define NT (K_DIM / BKB)        // 32 K-tiles

#define MFMA32(a, b, c) __builtin_amdgcn_mfma_i32_32x32x32_i8((a), (b), (c), 0, 0, 0)

template <typename OutT>
__device__ __forceinline__ void gemm_core(
    const int8_t* __restrict__ A, const int8_t* __restrict__ Bw,
    const float* __restrict__ adeq, float wsc,
    int m0, int n0, OutT* __restrict__ Cout) {
    __shared__ __align__(16) int8_t sA[4][BM2 * BKB];   // 4 x 16 KB
    __shared__ __align__(16) int8_t sB[4][BN2 * BKB];   // 4 x 16 KB
    int lane = threadIdx.x & 63;
    int wv = threadIdx.x >> 6;       // 0..7
    int wr = wv >> 2, wc = wv & 3;
    int r32 = lane & 31;             // row within a 32-row group
    int h32 = lane >> 5;             // 16B chunk within a 32B k-slice
    const int ag = wr * 4;           // first A group (of 8)
    const int bg = wc * 2;           // first B group (of 8)
    const int lb = lane * 16;        // linear frag byte offset

    const v16i vzero = {0, 0, 0, 0, 0, 0, 0, 0, 0, 0, 0, 0, 0, 0, 0, 0};
    v16i acc[4][2];
#pragma unroll
    for (int m = 0; m < 4; m++)
#pragma unroll
        for (int n = 0; n < 2; n++) acc[m][n] = vzero;

    // per-lane pre-permuted global source base (row = r32, 16B chunk = h32)
    const int8_t* Asrc = A + (size_t)(m0 + r32) * K_DIM + h32 * 16;
    const int8_t* Bsrc = Bw + (size_t)(n0 + r32) * K_DIM + h32 * 16;

    // wave wv stages A group wv + B group wv, both k-slices (4 gl_lds = 4 KB)
#define STG(c, kt) do {                                                                     \
    gl_lds16(Asrc + (size_t)(wv * 32) * K_DIM + (kt),      &sA[c][wv * 2048]);              \
    gl_lds16(Asrc + (size_t)(wv * 32) * K_DIM + (kt) + 32, &sA[c][wv * 2048 + 1024]);       \
    gl_lds16(Bsrc + (size_t)(wv * 32) * K_DIM + (kt),      &sB[c][wv * 2048]);              \
    gl_lds16(Bsrc + (size_t)(wv * 32) * K_DIM + (kt) + 32, &sB[c][wv * 2048 + 1024]);       \
  } while (0)

#define LDF(buf, grp, s) (*(const v4i*)(&(buf)[(grp) * 2048 + (s) * 1024 + lb]))

    // prologue: tiles 0 and 1
    STG(0, 0);
    STG(1, BKB);
    asm volatile("s_waitcnt vmcnt(4)" ::: "memory");   // tile 0 landed, tile 1 in flight
    wg_barrier();

    for (int t = 0; t < NT; ++t) {
        int cur = t & 3;
        const int8_t* bA = &sA[cur][0];
        const int8_t* bB = &sB[cur][0];

        // 12 fragment reads (plain loads -> compiler emits counted lgkmcnt)
        v4i af[4][2], bf[2][2];
#pragma unroll
        for (int m = 0; m < 4; m++) {
            af[m][0] = LDF(bA, ag + m, 0);
            af[m][1] = LDF(bA, ag + m, 1);
        }
#pragma unroll
        for (int n = 0; n < 2; n++) {
            bf[n][0] = LDF(bB, bg + n, 0);
            bf[n][1] = LDF(bB, bg + n, 1);
        }

        // prefetch tile t+2 into ring slot (t+2)&3 (issue early, land late)
        if (t + 2 < NT) STG((t + 2) & 3, (t + 2) * BKB);

        __builtin_amdgcn_s_setprio(1);
#pragma unroll
        for (int s = 0; s < 2; s++)
#pragma unroll
            for (int m = 0; m < 4; m++)
#pragma unroll
                for (int n = 0; n < 2; n++)
                    acc[m][n] = MFMA32(af[m][s], bf[n][s], acc[m][n]);
        __builtin_amdgcn_s_setprio(0);

        if (t + 1 < NT) {
            if (t + 2 < NT)
                asm volatile("s_waitcnt vmcnt(4)" ::: "memory");  // tile t+1 landed
            else
                asm volatile("s_waitcnt vmcnt(0)" ::: "memory");  // drain last stage
            wg_barrier();
        }
    }
#undef LDF
#undef STG

    // C/D 32x32 layout: col = lane&31, row = (r&3)+8*(r>>2)+4*(lane>>5)
#pragma unroll
    for (int m = 0; m < 4; m++) {
#pragma unroll
        for (int r = 0; r < 16; r++) {
            int rr = (r & 3) + 8 * (r >> 2) + 4 * h32;
            int row = m0 + (ag + m) * 32 + rr;
            float rs = adeq[row] * wsc;
            OutT* crow = Cout + (size_t)row * N_DIM + n0 + bg * 32 + r32;
            store_out(crow,      (float)acc[m][0][r] * rs);
            store_out(crow + 32, (float)acc[m][1][r] * rs);
        }
    }
}

// merged i/f/g GEMM: grid.x = 24 (8 N-tiles x 3 weights), grid.y = 32 M-tiles
__global__ __launch_bounds__(512, 2) void gemm_ifg(
    const int8_t* __restrict__ xq, const int8_t* __restrict__ wq,
    const float* __restrict__ adeq, const float* __restrict__ wdeq,
    bfraw* __restrict__ bufI, bfraw* __restrict__ bufF, bfraw* __restrict__ bufG) {
    int widx = blockIdx.x >> 3;
    int n0 = (blockIdx.x & 7) * BN2;
    int m0 = blockIdx.y * BM2;
    bfraw* outp = (widx == 0) ? bufI : ((widx == 1) ? bufF : bufG);
    gemm_core<bfraw>(xq, wq + (size_t)widx * WELEM, adeq, wdeq[widx], m0, n0, outp);
}

// final o GEMM: fp32 out. grid.x = 8, grid.y = 32
__global__ __launch_bounds__(512, 2) void gemm_o(
    const int8_t* __restrict__ oq, const int8_t* __restrict__ wq,
    const float* __restrict__ odeq, const float* __restrict__ wdeq,
    float* __restrict__ out) {
    gemm_core<float>(oq, wq + 3 * (size_t)WELEM, odeq, wdeq[3], blockIdx.y * BM2,
                     blockIdx.x * BN2, out);
}

// ---------------- chunked scan with fused activations ----------------
// f_t = sigmoid(fL_t); i_t = silu(iL_t)*(1-f_t); h_t = f_t*h_{t-1} + i_t
__global__ void scan1(const bfraw* __restrict__ iL, const bfraw* __restrict__ fL,
                      float* __restrict__ Fc, float* __restrict__ Ic) {
    int idx = blockIdx.x * 256 + threadIdx.x;   // 4*64*2048
    int d = idx & (D_DIM - 1);
    int c = (idx >> 11) & (NCH - 1);
    int b = idx >> 17;
    size_t base = ((size_t)(b * L_DIM + c * CHUNK)) * D_DIM + d;
    float F = 1.f, h = 0.f;
#pragma unroll 4
    for (int t = 0; t < CHUNK; t++) {
        float fr = bf2f(fL[base + (size_t)t * D_DIM]);
        float ir = bf2f(iL[base + (size_t)t * D_DIM]);
        float fv = sigmoidf_(fr);
        float iv = ir * sigmoidf_(ir) * (1.0f - fv);
        h = fv * h + iv;
        F *= fv;
    }
    size_t ci = ((size_t)b * NCH + c) * D_DIM + d;
    Fc[ci] = F;
    Ic[ci] = h;
}

__global__ void scan2(const float* __restrict__ Fc, const float* __restrict__ Ic,
                      float* __restrict__ Hc) {
    int idx = blockIdx.x * 256 + threadIdx.x;   // 8192
    int d = idx & (D_DIM - 1);
    int b = idx >> 11;
    float h = 0.f;
    for (int c0 = 0; c0 < NCH; c0 += 8) {
        float F[8], I[8];
#pragma unroll
        for (int j = 0; j < 8; j++) {
            size_t ci = ((size_t)b * NCH + c0 + j) * D_DIM + d;
            F[j] = Fc[ci];
            I[j] = Ic[ci];
        }
#pragma unroll
        for (int j = 0; j < 8; j++) {
            size_t ci = ((size_t)b * NCH + c0 + j) * D_DIM + d;
            Hc[ci] = h;
            h = F[j] * h + I[j];
        }
    }
}

__global__ void scan3(const bfraw* __restrict__ iL, const bfraw* __restrict__ fL,
                      const float* __restrict__ Hc, bfraw* __restrict__ hout) {
    int idx = blockIdx.x * 256 + threadIdx.x;
    int d = idx & (D_DIM - 1);
    int c = (idx >> 11) & (NCH - 1);
    int b = idx >> 17;
    size_t base = ((size_t)(b * L_DIM + c * CHUNK)) * D_DIM + d;
    float h = Hc[((size_t)b * NCH + c) * D_DIM + d];
#pragma unroll 4
    for (int t = 0; t < CHUNK; t++) {
        size_t a = base + (size_t)t * D_DIM;
        float fr = bf2f(fL[a]);
        float ir = bf2f(iL[a]);
        float fv = sigmoidf_(fr);
        float iv = ir * sigmoidf_(ir) * (1.0f - fv);
        h = fv * h + iv;
        hout[a] = f2bf(h);
    }
}

// ---------------- g-path: o = rmsnorm(g)*gw * h*sigmoid(h); rmsnorm+quant o ---------
union BF8 { uint4 u; bfraw s[8]; };

__global__ void gout_quant(const bfraw* __restrict__ gL, const bfraw* __restrict__ h,
                           const float* __restrict__ gw, int8_t* __restrict__ oq,
                           float* __restrict__ odeq) {
    int row = blockIdx.x, tid = threadIdx.x;
    BF8 g8, h8;
    g8.u = ((const uint4*)(gL + (size_t)row * D_DIM))[tid];
    float gv[8];
    float ss = 0.f;
#pragma unroll
    for (int j = 0; j < 8; j++) { gv[j] = bf2f(g8.s[j]); ss += gv[j] * gv[j]; }
    float ssg = block_sum256(ss);
    float invg = rsqrtf(ssg * (1.0f / (float)D_DIM) + 1e-5f);

    h8.u = ((const uint4*)(h + (size_t)row * D_DIM))[tid];
    const float4* wr = (const float4*)gw;
    float4 w0 = wr[2 * tid], w1 = wr[2 * tid + 1];
    float wv[8] = {w0.x, w0.y, w0.z, w0.w, w1.x, w1.y, w1.z, w1.w};
    float o[8];
    float sso = 0.f, amax = 0.f;
#pragma unroll
    for (int j = 0; j < 8; j++) {
        float hv = bf2f(h8.s[j]);
        o[j] = gv[j] * invg * wv[j] * hv * sigmoidf_(hv);
        sso += o[j] * o[j];
        amax = fmaxf(amax, fabsf(o[j]));
    }
    block_sum_max256(sso, amax);
    float invo = rsqrtf(sso * (1.0f / (float)D_DIM) + 1e-5f);
    float anc = fmaxf(amax * invo, 1e-5f);
    float s = 127.0f / anc;
    if (tid == 0) odeq[row] = anc * (1.0f / 127.0f);
    float sc = invo * s;
    int q[8];
#pragma unroll
    for (int j = 0; j < 8; j++) {
        int t = (int)rintf(o[j] * sc);
        q[j] = t < -128 ? -128 : (t > 127 ? 127 : t);
    }
    uint32_t lo = (uint32_t)(q[0] & 0xff) | ((uint32_t)(q[1] & 0xff) << 8) |
                  ((uint32_t)(q[2] & 0xff) << 16) | ((uint32_t)(q[3] & 0xff) << 24);
    uint32_t hi = (uint32_t)(q[4] & 0xff) | ((uint32_t)(q[5] & 0xff) << 8) |
                  ((uint32_t)(q[6] & 0xff) << 16) | ((uint32_t)(q[7] & 0xff) << 24);
    ((uint2*)(oq + (size_t)row * D_DIM))[tid] = make_uint2(lo, hi);
}

// ---------------- driver ----------------
extern "C" void kernel_launch(void* const* d_in, const int* in_sizes, int n_in,
                              void* d_out, int out_size, void* d_ws, size_t ws_size,
                              hipStream_t stream) {
    const float* x  = (const float*)d_in[0];
    const float* Wi = (const float*)d_in[1];
    const float* Wf = (const float*)d_in[2];
    const float* Wg = (const float*)d_in[3];
    const float* Wo = (const float*)d_in[4];
    const float* gw = (const float*)d_in[5];
    float* out = (float*)d_out;

    char* ws = (char*)d_ws;
    float*  wdeq  = (float*)(ws + 0);                 // 4 floats
    float*  wpart = (float*)(ws + 256);               // 512 partials
    float*  adeq  = (float*)(ws + 0x10000);           // 8192 per-row act dequant
    float*  odeq  = (float*)(ws + 0x20000);           // 8192 per-row o dequant
    int8_t* xq    = (int8_t*)(ws + 0x100000);         // 16MB int8 x; reused as oq
    int8_t* wq    = (int8_t*)(ws + 0x1100000);        // 4 x 4MB ternary weights
    float*  Fc    = (float*)(ws + 0x2100000);         // 2MB chunk f-products
    float*  Ic    = (float*)(ws + 0x2300000);         // 2MB chunk partial h
    float*  Hc    = (float*)(ws + 0x2500000);         // 2MB chunk carries
    bfraw*  bufI  = (bfraw*)(ws + 0x4000000);         // 32MB bf16: i_lin
    bfraw*  bufF  = (bfraw*)(ws + 0x6000000);         // 32MB bf16: f_lin
    bfraw*  bufG  = (bfraw*)(ws + 0x8000000);         // 32MB bf16: g_lin
    bfraw*  hbuf  = (bfraw*)(ws + 0xA000000);         // 32MB bf16: h

    wstats1<<<512, 256, 0, stream>>>(Wi, Wf, Wg, Wo, wpart);
    wstats2<<<1, 256, 0, stream>>>(wpart, wdeq);
    quant_all<<<16384 + 8192, 256, 0, stream>>>(Wi, Wf, Wg, Wo, wdeq, wq, x, xq, adeq);

    gemm_ifg<<<dim3(24, M_DIM / BM2), 512, 0, stream>>>(xq, wq, adeq, wdeq, bufI, bufF, bufG);

    scan1<<<2048, 256, 0, stream>>>(bufI, bufF, Fc, Ic);
    scan2<<<32, 256, 0, stream>>>(Fc, Ic, Hc);
    scan3<<<2048, 256, 0, stream>>>(bufI, bufF, Hc, hbuf);

    gout_quant<<<M_DIM, 256, 0, stream>>>(bufG, hbuf, gw, xq /*as oq*/, odeq);
    gemm_o<<<dim3(N_DIM / BN2, M_DIM / BM2), 512, 0, stream>>>(xq /*oq*/, wq, odeq, wdeq, out);

    (void)in_sizes; (void)n_in; (void)out_size; (void)ws_size;
}